// Round 9
// baseline (730.244 us; speedup 1.0000x reference)
//
#include <hip/hip_runtime.h>
#include <hip/hip_bf16.h>
#include <math.h>

#define BB 8
#define NN 2048
#define KK 20
#define XCCH 512
#define NSLOT 64
#define LEPS 1e-5f
#define NEGINF -3.4e38f

typedef __attribute__((ext_vector_type(8))) short s8v;
typedef __attribute__((ext_vector_type(8))) _Float16 h8v;
typedef __attribute__((ext_vector_type(4))) float f32x4;

__device__ __forceinline__ float lrelu(float x){ return x >= 0.f ? x : 0.2f*x; }

// ---------- transpose x (B,3,N) -> xt0 (B*N,4) fp32 ----------
__global__ __launch_bounds__(256) void k_transpose(const float* __restrict__ x, float* __restrict__ xt){
  int i = blockIdx.x*256 + threadIdx.x;
  if (i >= BB*NN) return;
  int b = i >> 11, n = i & (NN-1);
  float4 v;
  v.x = x[(b*3+0)*NN + n];
  v.y = x[(b*3+1)*NN + n];
  v.z = x[(b*3+2)*NN + n];
  v.w = 0.f;
  reinterpret_cast<float4*>(xt)[i] = v;
}

// ---------- weight fp32 -> bf16 slice with K padding ----------
__global__ __launch_bounds__(256) void k_cvtw(const float* __restrict__ W, __hip_bfloat16* __restrict__ Wb,
                                              int Cs, int coff, int Ccnt, int Cpad, int total){
  int i = blockIdx.x*256 + threadIdx.x;
  if (i >= total) return;
  int o = i / Cpad, c = i - o*Cpad;
  Wb[i] = (c < Ccnt) ? __float2bfloat16(W[(size_t)o*Cs + coff + c]) : __float2bfloat16(0.f);
}

// ---------- split P fp32 -> hi/lo f16 (Cpad cols, zero-padded) ----------
__global__ __launch_bounds__(256) void k_split(const float* __restrict__ P, int stride, int Ci, int Cpad,
    _Float16* __restrict__ Ph, _Float16* __restrict__ Pl){
  int i = blockIdx.x*256 + threadIdx.x;
  if (i >= BB*NN*Cpad) return;
  int p = i / Cpad, c = i - p*Cpad;
  float v = (c < Ci) ? P[(size_t)p*stride + c] : 0.f;
  _Float16 h = (_Float16)v;
  float r = v - (float)h;
  Ph[i] = h;
  Pl[i] = (_Float16)r;
}

// ---------- squared norms from the split representation (consistent with k_distm) ----------
__global__ __launch_bounds__(256) void k_sqs(const _Float16* __restrict__ Ph,
    const _Float16* __restrict__ Pl, int Cpad, float* __restrict__ sq){
  int i = blockIdx.x*256 + threadIdx.x;
  if (i >= BB*NN) return;
  const _Float16* ph = Ph + (size_t)i*Cpad;
  const _Float16* pl = Pl + (size_t)i*Cpad;
  float s = 0.f;
  for (int c = 0; c < Cpad; ++c){
    float v = (float)ph[c] + (float)pl[c];
    s += v*v;
  }
  sq[i] = s;
}

// ---------- MFMA pairwise score: pd = 2*dot - sq_n - sq_m; dot via f16 split (4 MFMA, exact) ----------
__global__ __launch_bounds__(256) void k_distm(
    const _Float16* __restrict__ Ph, const _Float16* __restrict__ Pl,
    int Cpad, int nchunk, const float* __restrict__ sq, float* __restrict__ pd)
{
  __shared__ _Float16 Ah[128*40];
  __shared__ _Float16 Al[128*40];
  __shared__ _Float16 Bh[128*40];
  __shared__ _Float16 Bl[128*40];
  int t = threadIdx.x;
  int w = t >> 6, lane = t & 63, m = lane & 15, quad = lane >> 4;
  int b = blockIdx.z;
  int n0 = blockIdx.y * 128, m0 = blockIdx.x * 128;
  const _Float16* PhB = Ph + (size_t)b*NN*Cpad;
  const _Float16* PlB = Pl + (size_t)b*NN*Cpad;
  f32x4 acc[2][8];
  #pragma unroll
  for (int s=0;s<2;s++)
    #pragma unroll
    for (int j=0;j<8;j++){ f32x4 z = {0.f,0.f,0.f,0.f}; acc[s][j] = z; }
  int r = t >> 1;
  int sg0 = t & 1;
  for (int ch=0; ch<nchunk; ++ch){
    int c0 = ch*32;
    #pragma unroll
    for (int k=0;k<2;k++){
      int seg = sg0 + 2*k;
      int go = c0 + seg*8;
      size_t an = (size_t)(n0+r)*Cpad + go;
      size_t bm = (size_t)(m0+r)*Cpad + go;
      *(h8v*)&Ah[r*40 + seg*8] = *(const h8v*)&PhB[an];
      *(h8v*)&Al[r*40 + seg*8] = *(const h8v*)&PlB[an];
      *(h8v*)&Bh[r*40 + seg*8] = *(const h8v*)&PhB[bm];
      *(h8v*)&Bl[r*40 + seg*8] = *(const h8v*)&PlB[bm];
    }
    __syncthreads();
    h8v ah0 = *(const h8v*)&Ah[(w*32 + m)*40 + quad*8];
    h8v al0 = *(const h8v*)&Al[(w*32 + m)*40 + quad*8];
    h8v ah1 = *(const h8v*)&Ah[(w*32 + 16 + m)*40 + quad*8];
    h8v al1 = *(const h8v*)&Al[(w*32 + 16 + m)*40 + quad*8];
    #pragma unroll
    for (int j=0;j<8;j++){
      h8v bh = *(const h8v*)&Bh[(j*16 + m)*40 + quad*8];
      h8v bl = *(const h8v*)&Bl[(j*16 + m)*40 + quad*8];
      acc[0][j] = __builtin_amdgcn_mfma_f32_16x16x32_f16(ah0, bh, acc[0][j], 0, 0, 0);
      acc[0][j] = __builtin_amdgcn_mfma_f32_16x16x32_f16(ah0, bl, acc[0][j], 0, 0, 0);
      acc[0][j] = __builtin_amdgcn_mfma_f32_16x16x32_f16(al0, bh, acc[0][j], 0, 0, 0);
      acc[0][j] = __builtin_amdgcn_mfma_f32_16x16x32_f16(al0, bl, acc[0][j], 0, 0, 0);
      acc[1][j] = __builtin_amdgcn_mfma_f32_16x16x32_f16(ah1, bh, acc[1][j], 0, 0, 0);
      acc[1][j] = __builtin_amdgcn_mfma_f32_16x16x32_f16(ah1, bl, acc[1][j], 0, 0, 0);
      acc[1][j] = __builtin_amdgcn_mfma_f32_16x16x32_f16(al1, bh, acc[1][j], 0, 0, 0);
      acc[1][j] = __builtin_amdgcn_mfma_f32_16x16x32_f16(al1, bl, acc[1][j], 0, 0, 0);
    }
    __syncthreads();
  }
  float sqm_[8];
  #pragma unroll
  for (int j=0;j<8;j++) sqm_[j] = sq[b*NN + m0 + j*16 + m];
  #pragma unroll
  for (int s=0;s<2;s++){
    int rbase = w*32 + s*16 + quad*4;
    #pragma unroll
    for (int rg=0; rg<4; rg++){
      float sqn = sq[b*NN + n0 + rbase + rg];
      size_t rowoff = ((size_t)b*NN + n0 + rbase + rg)*NN + m0 + m;
      #pragma unroll
      for (int j=0;j<8;j++){
        pd[rowoff + j*16] = 2.f*acc[s][j][rg] - sqn - sqm_[j];
      }
    }
  }
}

// ---------- top-20 per row: bulk extraction via per-lane top-2 invariant ----------
#define TK_REP32(F) F(0)F(1)F(2)F(3)F(4)F(5)F(6)F(7)F(8)F(9)F(10)F(11)F(12)F(13)F(14)F(15) \
                    F(16)F(17)F(18)F(19)F(20)F(21)F(22)F(23)F(24)F(25)F(26)F(27)F(28)F(29)F(30)F(31)
#define TK_SCAN(u) { bool c1 = r##u > p1; bool c2 = r##u > p2; \
                     p2 = c1 ? p1 : (c2 ? r##u : p2); i1 = c1 ? u : i1; p1 = c1 ? r##u : p1; }
#define TK_CLR(u)  r##u = (i1 == u) ? NEGINF : r##u;

__global__ __launch_bounds__(256) void k_topk(const float* __restrict__ pd, int* __restrict__ idxo){
  int t = threadIdx.x;
  int l = t & 63;
  int row = blockIdx.x*4 + (t >> 6);
  const float4* rp = (const float4*)(pd + (size_t)row*NN);
  float4 q0 = rp[0*64+l], q1 = rp[1*64+l], q2 = rp[2*64+l], q3 = rp[3*64+l];
  float4 q4 = rp[4*64+l], q5 = rp[5*64+l], q6 = rp[6*64+l], q7 = rp[7*64+l];
  float r0 =q0.x, r1 =q0.y, r2 =q0.z, r3 =q0.w, r4 =q1.x, r5 =q1.y, r6 =q1.z, r7 =q1.w;
  float r8 =q2.x, r9 =q2.y, r10=q2.z, r11=q2.w, r12=q3.x, r13=q3.y, r14=q3.z, r15=q3.w;
  float r16=q4.x, r17=q4.y, r18=q4.z, r19=q4.w, r20=q5.x, r21=q5.y, r22=q5.z, r23=q5.w;
  float r24=q6.x, r25=q6.y, r26=q6.z, r27=q6.w, r28=q7.x, r29=q7.y, r30=q7.z, r31=q7.w;
  float p1 = NEGINF, p2 = NEGINF; int i1 = 0;
  TK_REP32(TK_SCAN)
  int* orow = idxo + (size_t)row*KK;
  int got = 0;
  while (got < KK){
    float M2 = p2;
    #pragma unroll
    for (int off=1; off<64; off<<=1) M2 = fmaxf(M2, __shfl_xor(M2, off));
    bool ex = (p1 >= M2);
    unsigned long long ball = __ballot(ex);
    int cnt = __popcll(ball);
    int take = KK - got;
    if (cnt <= take){
      if (ex){
        int pos = got + __popcll(ball & ((1ull << l) - 1ull));
        orow[pos] = ((i1 >> 2) << 8) | (l << 2) | (i1 & 3);
      }
      got += cnt;
      if (ex && got < KK){
        TK_REP32(TK_CLR)
        p1 = NEGINF; p2 = NEGINF; i1 = 0;
        TK_REP32(TK_SCAN)
      }
    } else {
      for (int tt = 0; tt < take; ++tt){
        float wv = p1;
        #pragma unroll
        for (int off=1; off<64; off<<=1) wv = fmaxf(wv, __shfl_xor(wv, off));
        int gi = (p1 == wv) ? (((i1 >> 2) << 8) | (l << 2) | (i1 & 3)) : 0x7FFFFFFF;
        int cand = gi;
        #pragma unroll
        for (int off=1; off<64; off<<=1){
          int oc = __shfl_xor(cand, off);
          cand = oc < cand ? oc : cand;
        }
        if (gi == cand){
          orow[got + tt] = cand;
          p1 = NEGINF;
        }
      }
      got = KK;
    }
  }
}

// ---------- build W2 (2*Oi x Ci) fp32: rows [0,Oi) = W_diff, rows [Oi,2Oi) = W_ctr - W_diff ----------
__global__ __launch_bounds__(256) void k_wprep(const float* __restrict__ W, int Ci, int Oi,
                                               float* __restrict__ W2){
  int i = blockIdx.x*256 + threadIdx.x;
  if (i >= 2*Oi*Ci) return;
  int r = i / Ci, c = i - r*Ci;
  if (r < Oi){
    W2[i] = W[(size_t)r*2*Ci + Ci + c];
  } else {
    int o = r - Oi;
    W2[i] = W[(size_t)o*2*Ci + c] - W[(size_t)o*2*Ci + Ci + c];
  }
}

// ---------- U/D GEMM fp32 (exact): 128x128 tile, 8x8 acc/thread, b128 LDS reads ----------
// Accumulation order per output element identical to the 64x64 version (chunked c, j in order).
__global__ __launch_bounds__(256) void k_gemmud(const float* __restrict__ P, int stride, int Ci,
    const float* __restrict__ W2, int ostr, float* __restrict__ udb){
  __shared__ float Pt[16*132];   // [col][row] transposed, pad 132
  __shared__ float Wt[16*132];
  int t = threadIdx.x, ty = t >> 4, tx = t & 15;
  int p0 = blockIdx.x*128, o0 = blockIdx.y*128;
  float acc[8][8];
  #pragma unroll
  for (int i=0;i<8;i++)
    #pragma unroll
    for (int j=0;j<8;j++) acc[i][j]=0.f;
  for (int c0 = 0; c0 < Ci; c0 += 16){
    #pragma unroll
    for (int q=0;q<8;q++){
      int e = t + 256*q;            // 0..2047 -> 128 rows x 16 cols
      int r = e >> 4, cc = e & 15;
      int c = c0 + cc;
      bool ok = (c < Ci);
      Pt[cc*132 + r] = ok ? P[(size_t)(p0+r)*stride + c] : 0.f;
      Wt[cc*132 + r] = ok ? W2[(size_t)(o0+r)*Ci + c] : 0.f;
    }
    __syncthreads();
    #pragma unroll
    for (int j=0;j<16;j++){
      float4 a0 = *(const float4*)&Pt[j*132 + ty*8];
      float4 a1 = *(const float4*)&Pt[j*132 + ty*8 + 4];
      float4 b0 = *(const float4*)&Wt[j*132 + tx*8];
      float4 b1 = *(const float4*)&Wt[j*132 + tx*8 + 4];
      float a[8]  = {a0.x,a0.y,a0.z,a0.w,a1.x,a1.y,a1.z,a1.w};
      float bv[8] = {b0.x,b0.y,b0.z,b0.w,b1.x,b1.y,b1.z,b1.w};
      #pragma unroll
      for (int i=0;i<8;i++)
        #pragma unroll
        for (int jj=0;jj<8;jj++) acc[i][jj] += a[i]*bv[jj];
    }
    __syncthreads();
  }
  #pragma unroll
  for (int i=0;i<8;i++){
    size_t rowoff = (size_t)(p0+ty*8+i)*ostr + o0 + tx*8;
    *(float4*)&udb[rowoff]     = make_float4(acc[i][0], acc[i][1], acc[i][2], acc[i][3]);
    *(float4*)&udb[rowoff + 4] = make_float4(acc[i][4], acc[i][5], acc[i][6], acc[i][7]);
  }
}

// ---------- edge gather-reduce: y[n,k,o] = U[nbr(n,k),o] + D[n,o] ----------
__global__ __launch_bounds__(256) void k_edge(const float* __restrict__ udb, int ostr, int Oi,
    const int* __restrict__ idxg,
    float* __restrict__ ymax, float* __restrict__ ymin,
    float* __restrict__ chsum, float* __restrict__ chsq){
  __shared__ int lidx[16*KK];
  __shared__ float reds[2][4][64];
  int t = threadIdx.x, w = t >> 6, lane = t & 63;
  int n0 = blockIdx.x*16;           // global point index base (b*NN + n)
  int b  = n0 >> 11;
  int o0 = blockIdx.y*64;
  for (int q=t; q<16*KK; q+=256) lidx[q] = idxg[(size_t)n0*KK + q];
  __syncthreads();
  int o = o0 + lane;
  float ws_s = 0.f, ws_q = 0.f;
  #pragma unroll
  for (int p=0;p<4;p++){
    int pl = w*4 + p;
    int n = n0 + pl;
    float mx = -3.4e38f, mn = 3.4e38f, s = 0.f, s2 = 0.f;
    #pragma unroll
    for (int k=0;k<KK;k++){
      int nb = lidx[pl*KK + k];
      float u = udb[(size_t)((b<<11) + nb)*ostr + o];
      mx = fmaxf(mx, u); mn = fminf(mn, u);
      s += u; s2 += u*u;
    }
    float Dv = udb[(size_t)n*ostr + Oi + o];
    size_t base = (size_t)n*256 + o;
    ymax[base] = mx + Dv;
    ymin[base] = mn + Dv;
    ws_s += s + (float)KK*Dv;
    ws_q += s2 + 2.f*Dv*s + (float)KK*Dv*Dv;
  }
  reds[0][w][lane] = ws_s;
  reds[1][w][lane] = ws_q;
  __syncthreads();
  if (w == 0){
    float s = reds[0][0][lane] + reds[0][1][lane] + reds[0][2][lane] + reds[0][3][lane];
    float q = reds[1][0][lane] + reds[1][1][lane] + reds[1][2][lane] + reds[1][3][lane];
    int slot = blockIdx.x & (NSLOT-1);
    atomicAdd(&chsum[slot*256 + o], s);
    atomicAdd(&chsq [slot*256 + o], q);
  }
}

// ---------- BN stats finalize ----------
__global__ __launch_bounds__(256) void k_bnstats(const float* __restrict__ chsum, const float* __restrict__ chsq,
    const float* __restrict__ g, const float* __restrict__ bet,
    float* __restrict__ scl, float* __restrict__ shf, int Oi){
  int o = threadIdx.x;
  if (o >= Oi) return;
  float s=0.f, s2=0.f;
  for (int u=0;u<NSLOT;u++){ s += chsum[u*256+o]; s2 += chsq[u*256+o]; }
  float cnt = (float)(BB*NN*KK);
  float mean = s/cnt;
  float var = s2/cnt - mean*mean;
  float sc = g[o] / sqrtf(var + LEPS);
  scl[o] = sc;
  shf[o] = bet[o] - mean*sc;
}

// ---------- apply BN+LReLU, write fp32 xc + bf16 xcb ----------
__global__ __launch_bounds__(256) void k_apply(const float* __restrict__ ymax, const float* __restrict__ ymin,
    const float* __restrict__ scl, const float* __restrict__ shf,
    float* __restrict__ xc, __hip_bfloat16* __restrict__ xcb, int off, int Oi){
  int i = blockIdx.x*256 + threadIdx.x;
  if (i >= BB*NN*Oi) return;
  int o = i & (Oi-1);
  size_t p = (size_t)((unsigned)i / (unsigned)Oi);
  float sc = scl[o];
  float v = (sc >= 0.f) ? ymax[p*256+o] : ymin[p*256+o];
  float r = lrelu(v*sc + shf[o]);
  xc [p*XCCH + off + o] = r;
  xcb[p*XCCH + off + o] = __float2bfloat16(r);
}

// ---------- MFMA conv5: 128 pts x 128 outs per block, LDS-staged, fused stats epilogue ----------
__global__ __launch_bounds__(256) void k_conv5m(const __hip_bfloat16* __restrict__ xcb,
    const __hip_bfloat16* __restrict__ w5b,
    float* __restrict__ pmax, float* __restrict__ pmin,
    float* __restrict__ psum, float* __restrict__ psq)
{
  __shared__ __align__(16) char smem[20480];
  __hip_bfloat16* As = (__hip_bfloat16*)smem;
  __hip_bfloat16* Bs = (__hip_bfloat16*)(smem + 10240);
  float* red = (float*)smem;   // overlay after compute: [4 stats][4 waves][128]
  int t = threadIdx.x, w = t >> 6, lane = t & 63, m = lane & 15, quad = lane >> 4;
  int nbk = blockIdx.x;        // 0..15 (128 points each)
  int b = blockIdx.z;
  int o0 = blockIdx.y * 128;
  int n0 = nbk * 128;
  const __hip_bfloat16* Abase = xcb + (size_t)(b*NN + n0)*XCCH;
  const __hip_bfloat16* Bbase = w5b + (size_t)o0*XCCH;
  f32x4 acc[2][8];
  #pragma unroll
  for (int s=0;s<2;s++)
    #pragma unroll
    for (int j=0;j<8;j++){ f32x4 z = {0.f,0.f,0.f,0.f}; acc[s][j] = z; }
  int r = t >> 1;
  int sg0 = t & 1;
  for (int ch=0; ch<16; ++ch){
    int c0 = ch*32;
    #pragma unroll
    for (int k=0;k<2;k++){
      int seg = sg0 + 2*k;
      int go = c0 + seg*8;
      *(s8v*)&As[r*40 + seg*8] = *(const s8v*)&Abase[(size_t)r*XCCH + go];
      *(s8v*)&Bs[r*40 + seg*8] = *(const s8v*)&Bbase[(size_t)r*XCCH + go];
    }
    __syncthreads();
    s8v a0 = *(const s8v*)&As[(w*32 + m)*40 + quad*8];
    s8v a1 = *(const s8v*)&As[(w*32 + 16 + m)*40 + quad*8];
    #pragma unroll
    for (int j=0;j<8;j++){
      s8v bf = *(const s8v*)&Bs[(j*16 + m)*40 + quad*8];
      acc[0][j] = __builtin_amdgcn_mfma_f32_16x16x32_bf16(a0, bf, acc[0][j], 0, 0, 0);
      acc[1][j] = __builtin_amdgcn_mfma_f32_16x16x32_bf16(a1, bf, acc[1][j], 0, 0, 0);
    }
    __syncthreads();
  }
  // per-lane stats over its 8 rows (s in {0,1} x rg in {0..3}) per col frag j
  float mx[8], mn[8], sm[8], sq[8];
  #pragma unroll
  for (int j=0;j<8;j++){
    mx[j] = -3.4e38f; mn[j] = 3.4e38f; sm[j] = 0.f; sq[j] = 0.f;
    #pragma unroll
    for (int s=0;s<2;s++){
      f32x4 a = acc[s][j];
      #pragma unroll
      for (int rg=0; rg<4; rg++){
        float v = a[rg];
        mx[j] = fmaxf(mx[j], v); mn[j] = fminf(mn[j], v);
        sm[j] += v; sq[j] += v*v;
      }
    }
  }
  // cross-quad reduce (same col, rows differ by quad) -> all 32 rows of wave w
  #pragma unroll
  for (int j=0;j<8;j++){
    #pragma unroll
    for (int off=16; off<=32; off<<=1){
      mx[j] = fmaxf(mx[j], __shfl_xor(mx[j], off));
      mn[j] = fminf(mn[j], __shfl_xor(mn[j], off));
      sm[j] += __shfl_xor(sm[j], off);
      sq[j] += __shfl_xor(sq[j], off);
    }
  }
  if (quad == 0){
    #pragma unroll
    for (int j=0;j<8;j++){
      int c = j*16 + m;
      red[(0*4 + w)*128 + c] = mx[j];
      red[(1*4 + w)*128 + c] = mn[j];
      red[(2*4 + w)*128 + c] = sm[j];
      red[(3*4 + w)*128 + c] = sq[j];
    }
  }
  __syncthreads();
  if (t < 128){
    int c = t;
    float MX = red[(0*4+0)*128+c], MN = red[(1*4+0)*128+c];
    float S  = red[(2*4+0)*128+c], Q  = red[(3*4+0)*128+c];
    #pragma unroll
    for (int u=1;u<4;u++){
      MX = fmaxf(MX, red[(0*4+u)*128+c]);
      MN = fminf(MN, red[(1*4+u)*128+c]);
      S += red[(2*4+u)*128+c];
      Q += red[(3*4+u)*128+c];
    }
    size_t ii = ((size_t)b*1024 + o0 + c)*16 + nbk;
    pmax[ii] = MX; pmin[ii] = MN; psum[ii] = S; psq[ii] = Q;
  }
}

__global__ __launch_bounds__(256) void k_stats5(const float* __restrict__ psum, const float* __restrict__ psq,
    const float* __restrict__ g5, const float* __restrict__ b5,
    float* __restrict__ sc5, float* __restrict__ sh5){
  int o = blockIdx.x*256 + threadIdx.x;
  float s=0.f, s2=0.f;
  for (int b=0;b<BB;b++){
    const float* ps = &psum[((size_t)b*1024 + o)*16];
    const float* pq = &psq [((size_t)b*1024 + o)*16];
    #pragma unroll
    for (int u=0;u<16;u++){ s += ps[u]; s2 += pq[u]; }
  }
  float cnt = (float)(BB*NN);
  float mean = s/cnt;
  float var = s2/cnt - mean*mean;
  float sc = g5[o] / sqrtf(var + LEPS);
  sc5[o] = sc;
  sh5[o] = b5[o] - mean*sc;
}

__global__ __launch_bounds__(256) void k_apply5(const float* __restrict__ pmax, const float* __restrict__ pmin,
    const float* __restrict__ sc5, const float* __restrict__ sh5, float* __restrict__ out){
  int i = blockIdx.x*256 + threadIdx.x;
  int o = i & 1023;
  float sc = sc5[o];
  float v;
  if (sc >= 0.f){
    const float* p = &pmax[(size_t)i*16];
    v = p[0];
    #pragma unroll
    for (int u=1;u<16;u++) v = fmaxf(v, p[u]);
  } else {
    const float* p = &pmin[(size_t)i*16];
    v = p[0];
    #pragma unroll
    for (int u=1;u<16;u++) v = fminf(v, p[u]);
  }
  out[i] = lrelu(v*sc + sh5[o]);
}

extern "C" void kernel_launch(void* const* d_in, const int* in_sizes, int n_in,
                              void* d_out, int out_size, void* d_ws, size_t ws_size,
                              hipStream_t stream){
  const float* x  = (const float*)d_in[0];
  const float* w1 = (const float*)d_in[1];
  const float* g1 = (const float*)d_in[2];
  const float* b1 = (const float*)d_in[3];
  const float* w2 = (const float*)d_in[4];
  const float* g2 = (const float*)d_in[5];
  const float* b2 = (const float*)d_in[6];
  const float* w3 = (const float*)d_in[7];
  const float* g3 = (const float*)d_in[8];
  const float* b3 = (const float*)d_in[9];
  const float* w4 = (const float*)d_in[10];
  const float* g4 = (const float*)d_in[11];
  const float* b4 = (const float*)d_in[12];
  const float* w5 = (const float*)d_in[13];
  const float* g5 = (const float*)d_in[14];
  const float* b5 = (const float*)d_in[15];
  float* out = (float*)d_out;
  float* ws = (float*)d_ws;

  const size_t F_PD   = 0;
  const size_t F_XT0  = F_PD   + (size_t)BB*NN*NN;
  const size_t F_XC   = F_XT0  + (size_t)BB*NN*4;
  const size_t F_CHS  = F_XC   + (size_t)BB*NN*XCCH;
  const size_t F_CHQ  = F_CHS  + (size_t)NSLOT*256;
  const size_t F_SCL  = F_CHQ  + (size_t)NSLOT*256;
  const size_t F_SHF  = F_SCL  + 256;
  const size_t F_SQ   = F_SHF  + 256;
  const size_t F_IDX  = F_SQ   + (size_t)BB*NN;
  const size_t F_PMAX = F_IDX  + (size_t)BB*NN*KK;
  const size_t F_PMIN = F_PMAX + (size_t)BB*1024*8;
  const size_t F_PSUM = F_PMIN + (size_t)BB*1024*8;
  const size_t F_PSQ  = F_PSUM + (size_t)BB*1024*8;
  const size_t F_SC5  = F_PSQ  + (size_t)BB*1024*8;
  const size_t F_SH5  = F_SC5  + 1024;
  const size_t F_XCB  = F_SH5  + 1024;
  const size_t F_WB   = F_XCB  + (size_t)BB*NN*XCCH/2;      // wb region (bf16)
  const size_t F_PH   = F_WB   + 278528;                    // Ph: BB*NN*128 f16 = 1048576 floats
  const size_t F_PL   = F_PH   + 1048576;

  float* pd    = ws + F_PD;
  float* udb   = pd;                          // alias pd (pd dead after k_topk); <=8.4M floats
  float* w2buf = pd + (size_t)12*1024*1024;   // fp32 W2 (<=65536 floats), clear of udb & ymax
  float* ymax  = pd + (size_t)16*1024*1024;
  float* ymin  = pd + (size_t)21*1024*1024;
  // conv5 partials live in the pd region (dead after last k_apply): 16 slots per (b,o)
  float* pmax  = pd;
  float* pmin  = pd + (size_t)(1<<20);
  float* psum  = pd + (size_t)(2<<20);
  float* psq   = pd + (size_t)(3<<20);
  float* xt0   = ws + F_XT0;
  float* xc    = ws + F_XC;
  float* chsum = ws + F_CHS;
  float* chsq  = ws + F_CHQ;
  float* scl   = ws + F_SCL;
  float* shf   = ws + F_SHF;
  float* sqb   = ws + F_SQ;
  int*   idxb  = (int*)(ws + F_IDX);
  float* sc5   = ws + F_SC5;
  float* sh5   = ws + F_SH5;
  __hip_bfloat16* xcb = (__hip_bfloat16*)(ws + F_XCB);
  __hip_bfloat16* wb  = (__hip_bfloat16*)(ws + F_WB);
  __hip_bfloat16* w5b = wb + 32768;    // 1024x512
  _Float16* Ph  = (_Float16*)(ws + F_PH);
  _Float16* Pl  = (_Float16*)(ws + F_PL);

  (void)in_sizes; (void)n_in; (void)out_size; (void)ws_size;

  k_transpose<<<64, 256, 0, stream>>>(x, xt0);
  k_cvtw<<<(524288+255)/256, 256, 0, stream>>>(w5, w5b, 512, 0, 512, 512, 524288);

  struct LayerP { const float* P; int stride; int Ci; int CiD; int Cpad;
                  const float* W; const float* g; const float* b; int Oi; int off; };
  LayerP L[4] = {
    { xt0,    4,   3,   4,   32,  w1, g1, b1,  64, 0   },
    { xc,     512, 64,  64,  64,  w2, g2, b2,  64, 64  },
    { xc+64,  512, 64,  64,  64,  w3, g3, b3, 128, 128 },
    { xc+128, 512, 128, 128, 128, w4, g4, b4, 256, 256 },
  };

  for (int l=0; l<4; ++l){
    int Cpad = L[l].Cpad, nchunk = Cpad/32;
    int Oi = L[l].Oi, Ci = L[l].Ci;
    int ostr = 2*Oi;
    k_split<<<(BB*NN*Cpad+255)/256, 256, 0, stream>>>(L[l].P, L[l].stride, L[l].CiD, Cpad, Ph, Pl);
    k_sqs<<<64, 256, 0, stream>>>(Ph, Pl, Cpad, sqb);
    k_distm<<<dim3(16,16,8), 256, 0, stream>>>(Ph, Pl, Cpad, nchunk, sqb, pd);
    k_topk<<<BB*NN/4, 256, 0, stream>>>(pd, idxb);
    hipMemsetAsync(chsum, 0, (size_t)NSLOT*256*2*sizeof(float), stream);
    // pd is dead now: build W2 and the per-point U/D GEMM in its place (exact fp32)
    k_wprep<<<(2*Oi*Ci+255)/256, 256, 0, stream>>>(L[l].W, Ci, Oi, w2buf);
    k_gemmud<<<dim3(BB*NN/128, ostr/128), 256, 0, stream>>>(L[l].P, L[l].stride, Ci, w2buf, ostr, udb);
    k_edge<<<dim3(BB*NN/16, Oi/64), 256, 0, stream>>>(udb, ostr, Oi, idxb, ymax, ymin, chsum, chsq);
    k_bnstats<<<1, 256, 0, stream>>>(chsum, chsq, L[l].g, L[l].b, scl, shf, Oi);
    k_apply<<<(BB*NN*Oi + 255)/256, 256, 0, stream>>>(ymax, ymin, scl, shf, xc, xcb, L[l].off, Oi);
  }

  k_conv5m<<<dim3(16, 8, BB), 256, 0, stream>>>(xcb, w5b, pmax, pmin, psum, psq);
  k_stats5<<<4, 256, 0, stream>>>(psum, psq, g5, b5, sc5, sh5);
  k_apply5<<<(BB*1024)/256, 256, 0, stream>>>(pmax, pmin, sc5, sh5, out);
}

// Round 10
// 682.208 us; speedup vs baseline: 1.0704x; 1.0704x over previous
//
#include <hip/hip_runtime.h>
#include <hip/hip_bf16.h>
#include <math.h>

#define BB 8
#define NN 2048
#define KK 20
#define XCCH 512
#define NSLOT 64
#define LEPS 1e-5f
#define NEGINF -3.4e38f

typedef __attribute__((ext_vector_type(8))) short s8v;
typedef __attribute__((ext_vector_type(8))) _Float16 h8v;
typedef __attribute__((ext_vector_type(4))) float f32x4;

__device__ __forceinline__ float lrelu(float x){ return x >= 0.f ? x : 0.2f*x; }

// ---------- transpose x (B,3,N) -> xt0 (B*N,4) fp32 ----------
__global__ __launch_bounds__(256) void k_transpose(const float* __restrict__ x, float* __restrict__ xt){
  int i = blockIdx.x*256 + threadIdx.x;
  if (i >= BB*NN) return;
  int b = i >> 11, n = i & (NN-1);
  float4 v;
  v.x = x[(b*3+0)*NN + n];
  v.y = x[(b*3+1)*NN + n];
  v.z = x[(b*3+2)*NN + n];
  v.w = 0.f;
  reinterpret_cast<float4*>(xt)[i] = v;
}

// ---------- weight fp32 -> bf16 slice with K padding ----------
__global__ __launch_bounds__(256) void k_cvtw(const float* __restrict__ W, __hip_bfloat16* __restrict__ Wb,
                                              int Cs, int coff, int Ccnt, int Cpad, int total){
  int i = blockIdx.x*256 + threadIdx.x;
  if (i >= total) return;
  int o = i / Cpad, c = i - o*Cpad;
  Wb[i] = (c < Ccnt) ? __float2bfloat16(W[(size_t)o*Cs + coff + c]) : __float2bfloat16(0.f);
}

// ---------- split P fp32 -> hi/lo f16 (Cpad cols, zero-padded) ----------
__global__ __launch_bounds__(256) void k_split(const float* __restrict__ P, int stride, int Ci, int Cpad,
    _Float16* __restrict__ Ph, _Float16* __restrict__ Pl){
  int i = blockIdx.x*256 + threadIdx.x;
  if (i >= BB*NN*Cpad) return;
  int p = i / Cpad, c = i - p*Cpad;
  float v = (c < Ci) ? P[(size_t)p*stride + c] : 0.f;
  _Float16 h = (_Float16)v;
  float r = v - (float)h;
  Ph[i] = h;
  Pl[i] = (_Float16)r;
}

// ---------- squared norms from the split representation (consistent with k_distm) ----------
__global__ __launch_bounds__(256) void k_sqs(const _Float16* __restrict__ Ph,
    const _Float16* __restrict__ Pl, int Cpad, float* __restrict__ sq){
  int i = blockIdx.x*256 + threadIdx.x;
  if (i >= BB*NN) return;
  const _Float16* ph = Ph + (size_t)i*Cpad;
  const _Float16* pl = Pl + (size_t)i*Cpad;
  float s = 0.f;
  for (int c = 0; c < Cpad; ++c){
    float v = (float)ph[c] + (float)pl[c];
    s += v*v;
  }
  sq[i] = s;
}

// ---------- MFMA pairwise score: pd = 2*dot - sq_n - sq_m; dot via f16 split (4 MFMA, exact) ----------
__global__ __launch_bounds__(256) void k_distm(
    const _Float16* __restrict__ Ph, const _Float16* __restrict__ Pl,
    int Cpad, int nchunk, const float* __restrict__ sq, float* __restrict__ pd)
{
  __shared__ _Float16 Ah[128*40];
  __shared__ _Float16 Al[128*40];
  __shared__ _Float16 Bh[128*40];
  __shared__ _Float16 Bl[128*40];
  int t = threadIdx.x;
  int w = t >> 6, lane = t & 63, m = lane & 15, quad = lane >> 4;
  int b = blockIdx.z;
  int n0 = blockIdx.y * 128, m0 = blockIdx.x * 128;
  const _Float16* PhB = Ph + (size_t)b*NN*Cpad;
  const _Float16* PlB = Pl + (size_t)b*NN*Cpad;
  f32x4 acc[2][8];
  #pragma unroll
  for (int s=0;s<2;s++)
    #pragma unroll
    for (int j=0;j<8;j++){ f32x4 z = {0.f,0.f,0.f,0.f}; acc[s][j] = z; }
  int r = t >> 1;
  int sg0 = t & 1;
  for (int ch=0; ch<nchunk; ++ch){
    int c0 = ch*32;
    #pragma unroll
    for (int k=0;k<2;k++){
      int seg = sg0 + 2*k;
      int go = c0 + seg*8;
      size_t an = (size_t)(n0+r)*Cpad + go;
      size_t bm = (size_t)(m0+r)*Cpad + go;
      *(h8v*)&Ah[r*40 + seg*8] = *(const h8v*)&PhB[an];
      *(h8v*)&Al[r*40 + seg*8] = *(const h8v*)&PlB[an];
      *(h8v*)&Bh[r*40 + seg*8] = *(const h8v*)&PhB[bm];
      *(h8v*)&Bl[r*40 + seg*8] = *(const h8v*)&PlB[bm];
    }
    __syncthreads();
    h8v ah0 = *(const h8v*)&Ah[(w*32 + m)*40 + quad*8];
    h8v al0 = *(const h8v*)&Al[(w*32 + m)*40 + quad*8];
    h8v ah1 = *(const h8v*)&Ah[(w*32 + 16 + m)*40 + quad*8];
    h8v al1 = *(const h8v*)&Al[(w*32 + 16 + m)*40 + quad*8];
    #pragma unroll
    for (int j=0;j<8;j++){
      h8v bh = *(const h8v*)&Bh[(j*16 + m)*40 + quad*8];
      h8v bl = *(const h8v*)&Bl[(j*16 + m)*40 + quad*8];
      acc[0][j] = __builtin_amdgcn_mfma_f32_16x16x32_f16(ah0, bh, acc[0][j], 0, 0, 0);
      acc[0][j] = __builtin_amdgcn_mfma_f32_16x16x32_f16(ah0, bl, acc[0][j], 0, 0, 0);
      acc[0][j] = __builtin_amdgcn_mfma_f32_16x16x32_f16(al0, bh, acc[0][j], 0, 0, 0);
      acc[0][j] = __builtin_amdgcn_mfma_f32_16x16x32_f16(al0, bl, acc[0][j], 0, 0, 0);
      acc[1][j] = __builtin_amdgcn_mfma_f32_16x16x32_f16(ah1, bh, acc[1][j], 0, 0, 0);
      acc[1][j] = __builtin_amdgcn_mfma_f32_16x16x32_f16(ah1, bl, acc[1][j], 0, 0, 0);
      acc[1][j] = __builtin_amdgcn_mfma_f32_16x16x32_f16(al1, bh, acc[1][j], 0, 0, 0);
      acc[1][j] = __builtin_amdgcn_mfma_f32_16x16x32_f16(al1, bl, acc[1][j], 0, 0, 0);
    }
    __syncthreads();
  }
  float sqm_[8];
  #pragma unroll
  for (int j=0;j<8;j++) sqm_[j] = sq[b*NN + m0 + j*16 + m];
  #pragma unroll
  for (int s=0;s<2;s++){
    int rbase = w*32 + s*16 + quad*4;
    #pragma unroll
    for (int rg=0; rg<4; rg++){
      float sqn = sq[b*NN + n0 + rbase + rg];
      size_t rowoff = ((size_t)b*NN + n0 + rbase + rg)*NN + m0 + m;
      #pragma unroll
      for (int j=0;j<8;j++){
        pd[rowoff + j*16] = 2.f*acc[s][j][rg] - sqn - sqm_[j];
      }
    }
  }
}

// ---------- top-20 per row: bulk extraction via per-lane top-2 invariant ----------
#define TK_REP32(F) F(0)F(1)F(2)F(3)F(4)F(5)F(6)F(7)F(8)F(9)F(10)F(11)F(12)F(13)F(14)F(15) \
                    F(16)F(17)F(18)F(19)F(20)F(21)F(22)F(23)F(24)F(25)F(26)F(27)F(28)F(29)F(30)F(31)
#define TK_SCAN(u) { bool c1 = r##u > p1; bool c2 = r##u > p2; \
                     p2 = c1 ? p1 : (c2 ? r##u : p2); i1 = c1 ? u : i1; p1 = c1 ? r##u : p1; }
#define TK_CLR(u)  r##u = (i1 == u) ? NEGINF : r##u;

__global__ __launch_bounds__(256) void k_topk(const float* __restrict__ pd, int* __restrict__ idxo){
  int t = threadIdx.x;
  int l = t & 63;
  int row = blockIdx.x*4 + (t >> 6);
  const float4* rp = (const float4*)(pd + (size_t)row*NN);
  float4 q0 = rp[0*64+l], q1 = rp[1*64+l], q2 = rp[2*64+l], q3 = rp[3*64+l];
  float4 q4 = rp[4*64+l], q5 = rp[5*64+l], q6 = rp[6*64+l], q7 = rp[7*64+l];
  float r0 =q0.x, r1 =q0.y, r2 =q0.z, r3 =q0.w, r4 =q1.x, r5 =q1.y, r6 =q1.z, r7 =q1.w;
  float r8 =q2.x, r9 =q2.y, r10=q2.z, r11=q2.w, r12=q3.x, r13=q3.y, r14=q3.z, r15=q3.w;
  float r16=q4.x, r17=q4.y, r18=q4.z, r19=q4.w, r20=q5.x, r21=q5.y, r22=q5.z, r23=q5.w;
  float r24=q6.x, r25=q6.y, r26=q6.z, r27=q6.w, r28=q7.x, r29=q7.y, r30=q7.z, r31=q7.w;
  float p1 = NEGINF, p2 = NEGINF; int i1 = 0;
  TK_REP32(TK_SCAN)
  int* orow = idxo + (size_t)row*KK;
  int got = 0;
  while (got < KK){
    float M2 = p2;
    #pragma unroll
    for (int off=1; off<64; off<<=1) M2 = fmaxf(M2, __shfl_xor(M2, off));
    bool ex = (p1 >= M2);
    unsigned long long ball = __ballot(ex);
    int cnt = __popcll(ball);
    int take = KK - got;
    if (cnt <= take){
      if (ex){
        int pos = got + __popcll(ball & ((1ull << l) - 1ull));
        orow[pos] = ((i1 >> 2) << 8) | (l << 2) | (i1 & 3);
      }
      got += cnt;
      if (ex && got < KK){
        TK_REP32(TK_CLR)
        p1 = NEGINF; p2 = NEGINF; i1 = 0;
        TK_REP32(TK_SCAN)
      }
    } else {
      for (int tt = 0; tt < take; ++tt){
        float wv = p1;
        #pragma unroll
        for (int off=1; off<64; off<<=1) wv = fmaxf(wv, __shfl_xor(wv, off));
        int gi = (p1 == wv) ? (((i1 >> 2) << 8) | (l << 2) | (i1 & 3)) : 0x7FFFFFFF;
        int cand = gi;
        #pragma unroll
        for (int off=1; off<64; off<<=1){
          int oc = __shfl_xor(cand, off);
          cand = oc < cand ? oc : cand;
        }
        if (gi == cand){
          orow[got + tt] = cand;
          p1 = NEGINF;
        }
      }
      got = KK;
    }
  }
}

// ---------- build W2 (2*Oi x Ci) fp32: rows [0,Oi) = W_diff, rows [Oi,2Oi) = W_ctr - W_diff ----------
__global__ __launch_bounds__(256) void k_wprep(const float* __restrict__ W, int Ci, int Oi,
                                               float* __restrict__ W2){
  int i = blockIdx.x*256 + threadIdx.x;
  if (i >= 2*Oi*Ci) return;
  int r = i / Ci, c = i - r*Ci;
  if (r < Oi){
    W2[i] = W[(size_t)r*2*Ci + Ci + c];
  } else {
    int o = r - Oi;
    W2[i] = W[(size_t)o*2*Ci + c] - W[(size_t)o*2*Ci + Ci + c];
  }
}

// ---------- U/D GEMM fp32 (exact): 64x64 tile, transposed LDS, b128 reads ----------
// Same accumulation values/order as the proven 64x64 version (bit-identical).
__global__ __launch_bounds__(256) void k_gemmud(const float* __restrict__ P, int stride, int Ci,
    const float* __restrict__ W2, int ostr, float* __restrict__ udb){
  __shared__ float Pt[16*68];   // [col][row], pitch 68 (68*4B = 272B, 16B-aligned rows)
  __shared__ float Wt[16*68];
  int t = threadIdx.x, ty = t >> 4, tx = t & 15;
  int p0 = blockIdx.x*64, o0 = blockIdx.y*64;
  float acc[4][4];
  #pragma unroll
  for (int i=0;i<4;i++)
    #pragma unroll
    for (int j=0;j<4;j++) acc[i][j]=0.f;
  for (int c0 = 0; c0 < Ci; c0 += 16){
    #pragma unroll
    for (int q=0;q<4;q++){
      int e = t + 256*q;
      int r = e >> 4, cc = e & 15;
      int c = c0 + cc;
      bool ok = (c < Ci);
      Pt[cc*68 + r] = ok ? P[(size_t)(p0+r)*stride + c] : 0.f;
      Wt[cc*68 + r] = ok ? W2[(size_t)(o0+r)*Ci + c] : 0.f;
    }
    __syncthreads();
    #pragma unroll
    for (int j=0;j<16;j++){
      float4 av  = *(const float4*)&Pt[j*68 + ty*4];   // broadcast across 16 lanes
      float4 bv4 = *(const float4*)&Wt[j*68 + tx*4];   // 256B contiguous per wave
      float a[4]  = {av.x, av.y, av.z, av.w};
      float bv[4] = {bv4.x, bv4.y, bv4.z, bv4.w};
      #pragma unroll
      for (int i=0;i<4;i++)
        #pragma unroll
        for (int jj=0;jj<4;jj++) acc[i][jj] += a[i]*bv[jj];
    }
    __syncthreads();
  }
  #pragma unroll
  for (int i=0;i<4;i++){
    *(float4*)&udb[(size_t)(p0+ty*4+i)*ostr + o0 + tx*4] =
      make_float4(acc[i][0], acc[i][1], acc[i][2], acc[i][3]);
  }
}

// ---------- edge gather-reduce: y[n,k,o] = U[nbr(n,k),o] + D[n,o] ----------
__global__ __launch_bounds__(256) void k_edge(const float* __restrict__ udb, int ostr, int Oi,
    const int* __restrict__ idxg,
    float* __restrict__ ymax, float* __restrict__ ymin,
    float* __restrict__ chsum, float* __restrict__ chsq){
  __shared__ int lidx[16*KK];
  __shared__ float reds[2][4][64];
  int t = threadIdx.x, w = t >> 6, lane = t & 63;
  int n0 = blockIdx.x*16;           // global point index base (b*NN + n)
  int b  = n0 >> 11;
  int o0 = blockIdx.y*64;
  for (int q=t; q<16*KK; q+=256) lidx[q] = idxg[(size_t)n0*KK + q];
  __syncthreads();
  int o = o0 + lane;
  float ws_s = 0.f, ws_q = 0.f;
  #pragma unroll
  for (int p=0;p<4;p++){
    int pl = w*4 + p;
    int n = n0 + pl;
    float mx = -3.4e38f, mn = 3.4e38f, s = 0.f, s2 = 0.f;
    #pragma unroll
    for (int k=0;k<KK;k++){
      int nb = lidx[pl*KK + k];
      float u = udb[(size_t)((b<<11) + nb)*ostr + o];
      mx = fmaxf(mx, u); mn = fminf(mn, u);
      s += u; s2 += u*u;
    }
    float Dv = udb[(size_t)n*ostr + Oi + o];
    size_t base = (size_t)n*256 + o;
    ymax[base] = mx + Dv;
    ymin[base] = mn + Dv;
    ws_s += s + (float)KK*Dv;
    ws_q += s2 + 2.f*Dv*s + (float)KK*Dv*Dv;
  }
  reds[0][w][lane] = ws_s;
  reds[1][w][lane] = ws_q;
  __syncthreads();
  if (w == 0){
    float s = reds[0][0][lane] + reds[0][1][lane] + reds[0][2][lane] + reds[0][3][lane];
    float q = reds[1][0][lane] + reds[1][1][lane] + reds[1][2][lane] + reds[1][3][lane];
    int slot = blockIdx.x & (NSLOT-1);
    atomicAdd(&chsum[slot*256 + o], s);
    atomicAdd(&chsq [slot*256 + o], q);
  }
}

// ---------- BN stats finalize ----------
__global__ __launch_bounds__(256) void k_bnstats(const float* __restrict__ chsum, const float* __restrict__ chsq,
    const float* __restrict__ g, const float* __restrict__ bet,
    float* __restrict__ scl, float* __restrict__ shf, int Oi){
  int o = threadIdx.x;
  if (o >= Oi) return;
  float s=0.f, s2=0.f;
  for (int u=0;u<NSLOT;u++){ s += chsum[u*256+o]; s2 += chsq[u*256+o]; }
  float cnt = (float)(BB*NN*KK);
  float mean = s/cnt;
  float var = s2/cnt - mean*mean;
  float sc = g[o] / sqrtf(var + LEPS);
  scl[o] = sc;
  shf[o] = bet[o] - mean*sc;
}

// ---------- apply BN+LReLU, write fp32 xc + bf16 xcb ----------
__global__ __launch_bounds__(256) void k_apply(const float* __restrict__ ymax, const float* __restrict__ ymin,
    const float* __restrict__ scl, const float* __restrict__ shf,
    float* __restrict__ xc, __hip_bfloat16* __restrict__ xcb, int off, int Oi){
  int i = blockIdx.x*256 + threadIdx.x;
  if (i >= BB*NN*Oi) return;
  int o = i & (Oi-1);
  size_t p = (size_t)((unsigned)i / (unsigned)Oi);
  float sc = scl[o];
  float v = (sc >= 0.f) ? ymax[p*256+o] : ymin[p*256+o];
  float r = lrelu(v*sc + shf[o]);
  xc [p*XCCH + off + o] = r;
  xcb[p*XCCH + off + o] = __float2bfloat16(r);
}

// ---------- MFMA conv5: 128 pts x 128 outs per block, LDS-staged, fused stats epilogue ----------
__global__ __launch_bounds__(256) void k_conv5m(const __hip_bfloat16* __restrict__ xcb,
    const __hip_bfloat16* __restrict__ w5b,
    float* __restrict__ pmax, float* __restrict__ pmin,
    float* __restrict__ psum, float* __restrict__ psq)
{
  __shared__ __align__(16) char smem[20480];
  __hip_bfloat16* As = (__hip_bfloat16*)smem;
  __hip_bfloat16* Bs = (__hip_bfloat16*)(smem + 10240);
  float* red = (float*)smem;   // overlay after compute: [4 stats][4 waves][128]
  int t = threadIdx.x, w = t >> 6, lane = t & 63, m = lane & 15, quad = lane >> 4;
  int nbk = blockIdx.x;        // 0..15 (128 points each)
  int b = blockIdx.z;
  int o0 = blockIdx.y * 128;
  int n0 = nbk * 128;
  const __hip_bfloat16* Abase = xcb + (size_t)(b*NN + n0)*XCCH;
  const __hip_bfloat16* Bbase = w5b + (size_t)o0*XCCH;
  f32x4 acc[2][8];
  #pragma unroll
  for (int s=0;s<2;s++)
    #pragma unroll
    for (int j=0;j<8;j++){ f32x4 z = {0.f,0.f,0.f,0.f}; acc[s][j] = z; }
  int r = t >> 1;
  int sg0 = t & 1;
  for (int ch=0; ch<16; ++ch){
    int c0 = ch*32;
    #pragma unroll
    for (int k=0;k<2;k++){
      int seg = sg0 + 2*k;
      int go = c0 + seg*8;
      *(s8v*)&As[r*40 + seg*8] = *(const s8v*)&Abase[(size_t)r*XCCH + go];
      *(s8v*)&Bs[r*40 + seg*8] = *(const s8v*)&Bbase[(size_t)r*XCCH + go];
    }
    __syncthreads();
    s8v a0 = *(const s8v*)&As[(w*32 + m)*40 + quad*8];
    s8v a1 = *(const s8v*)&As[(w*32 + 16 + m)*40 + quad*8];
    #pragma unroll
    for (int j=0;j<8;j++){
      s8v bf = *(const s8v*)&Bs[(j*16 + m)*40 + quad*8];
      acc[0][j] = __builtin_amdgcn_mfma_f32_16x16x32_bf16(a0, bf, acc[0][j], 0, 0, 0);
      acc[1][j] = __builtin_amdgcn_mfma_f32_16x16x32_bf16(a1, bf, acc[1][j], 0, 0, 0);
    }
    __syncthreads();
  }
  // per-lane stats over its 8 rows (s in {0,1} x rg in {0..3}) per col frag j
  float mx[8], mn[8], sm[8], sq[8];
  #pragma unroll
  for (int j=0;j<8;j++){
    mx[j] = -3.4e38f; mn[j] = 3.4e38f; sm[j] = 0.f; sq[j] = 0.f;
    #pragma unroll
    for (int s=0;s<2;s++){
      f32x4 a = acc[s][j];
      #pragma unroll
      for (int rg=0; rg<4; rg++){
        float v = a[rg];
        mx[j] = fmaxf(mx[j], v); mn[j] = fminf(mn[j], v);
        sm[j] += v; sq[j] += v*v;
      }
    }
  }
  // cross-quad reduce (same col, rows differ by quad) -> all 32 rows of wave w
  #pragma unroll
  for (int j=0;j<8;j++){
    #pragma unroll
    for (int off=16; off<=32; off<<=1){
      mx[j] = fmaxf(mx[j], __shfl_xor(mx[j], off));
      mn[j] = fminf(mn[j], __shfl_xor(mn[j], off));
      sm[j] += __shfl_xor(sm[j], off);
      sq[j] += __shfl_xor(sq[j], off);
    }
  }
  if (quad == 0){
    #pragma unroll
    for (int j=0;j<8;j++){
      int c = j*16 + m;
      red[(0*4 + w)*128 + c] = mx[j];
      red[(1*4 + w)*128 + c] = mn[j];
      red[(2*4 + w)*128 + c] = sm[j];
      red[(3*4 + w)*128 + c] = sq[j];
    }
  }
  __syncthreads();
  if (t < 128){
    int c = t;
    float MX = red[(0*4+0)*128+c], MN = red[(1*4+0)*128+c];
    float S  = red[(2*4+0)*128+c], Q  = red[(3*4+0)*128+c];
    #pragma unroll
    for (int u=1;u<4;u++){
      MX = fmaxf(MX, red[(0*4+u)*128+c]);
      MN = fminf(MN, red[(1*4+u)*128+c]);
      S += red[(2*4+u)*128+c];
      Q += red[(3*4+u)*128+c];
    }
    size_t ii = ((size_t)b*1024 + o0 + c)*16 + nbk;
    pmax[ii] = MX; pmin[ii] = MN; psum[ii] = S; psq[ii] = Q;
  }
}

__global__ __launch_bounds__(256) void k_stats5(const float* __restrict__ psum, const float* __restrict__ psq,
    const float* __restrict__ g5, const float* __restrict__ b5,
    float* __restrict__ sc5, float* __restrict__ sh5){
  int o = blockIdx.x*256 + threadIdx.x;
  float s=0.f, s2=0.f;
  for (int b=0;b<BB;b++){
    const float* ps = &psum[((size_t)b*1024 + o)*16];
    const float* pq = &psq [((size_t)b*1024 + o)*16];
    #pragma unroll
    for (int u=0;u<16;u++){ s += ps[u]; s2 += pq[u]; }
  }
  float cnt = (float)(BB*NN);
  float mean = s/cnt;
  float var = s2/cnt - mean*mean;
  float sc = g5[o] / sqrtf(var + LEPS);
  sc5[o] = sc;
  sh5[o] = b5[o] - mean*sc;
}

__global__ __launch_bounds__(256) void k_apply5(const float* __restrict__ pmax, const float* __restrict__ pmin,
    const float* __restrict__ sc5, const float* __restrict__ sh5, float* __restrict__ out){
  int i = blockIdx.x*256 + threadIdx.x;
  int o = i & 1023;
  float sc = sc5[o];
  float v;
  if (sc >= 0.f){
    const float* p = &pmax[(size_t)i*16];
    v = p[0];
    #pragma unroll
    for (int u=1;u<16;u++) v = fmaxf(v, p[u]);
  } else {
    const float* p = &pmin[(size_t)i*16];
    v = p[0];
    #pragma unroll
    for (int u=1;u<16;u++) v = fminf(v, p[u]);
  }
  out[i] = lrelu(v*sc + sh5[o]);
}

extern "C" void kernel_launch(void* const* d_in, const int* in_sizes, int n_in,
                              void* d_out, int out_size, void* d_ws, size_t ws_size,
                              hipStream_t stream){
  const float* x  = (const float*)d_in[0];
  const float* w1 = (const float*)d_in[1];
  const float* g1 = (const float*)d_in[2];
  const float* b1 = (const float*)d_in[3];
  const float* w2 = (const float*)d_in[4];
  const float* g2 = (const float*)d_in[5];
  const float* b2 = (const float*)d_in[6];
  const float* w3 = (const float*)d_in[7];
  const float* g3 = (const float*)d_in[8];
  const float* b3 = (const float*)d_in[9];
  const float* w4 = (const float*)d_in[10];
  const float* g4 = (const float*)d_in[11];
  const float* b4 = (const float*)d_in[12];
  const float* w5 = (const float*)d_in[13];
  const float* g5 = (const float*)d_in[14];
  const float* b5 = (const float*)d_in[15];
  float* out = (float*)d_out;
  float* ws = (float*)d_ws;

  const size_t F_PD   = 0;
  const size_t F_XT0  = F_PD   + (size_t)BB*NN*NN;
  const size_t F_XC   = F_XT0  + (size_t)BB*NN*4;
  const size_t F_CHS  = F_XC   + (size_t)BB*NN*XCCH;
  const size_t F_CHQ  = F_CHS  + (size_t)NSLOT*256;
  const size_t F_SCL  = F_CHQ  + (size_t)NSLOT*256;
  const size_t F_SHF  = F_SCL  + 256;
  const size_t F_SQ   = F_SHF  + 256;
  const size_t F_IDX  = F_SQ   + (size_t)BB*NN;
  const size_t F_PMAX = F_IDX  + (size_t)BB*NN*KK;
  const size_t F_PMIN = F_PMAX + (size_t)BB*1024*8;
  const size_t F_PSUM = F_PMIN + (size_t)BB*1024*8;
  const size_t F_PSQ  = F_PSUM + (size_t)BB*1024*8;
  const size_t F_SC5  = F_PSQ  + (size_t)BB*1024*8;
  const size_t F_SH5  = F_SC5  + 1024;
  const size_t F_XCB  = F_SH5  + 1024;
  const size_t F_WB   = F_XCB  + (size_t)BB*NN*XCCH/2;      // wb region (bf16)
  const size_t F_PH   = F_WB   + 278528;                    // Ph: BB*NN*128 f16 = 1048576 floats
  const size_t F_PL   = F_PH   + 1048576;

  float* pd    = ws + F_PD;
  float* udb   = pd;                          // alias pd (pd dead after k_topk); <=8.4M floats
  float* w2buf = pd + (size_t)12*1024*1024;   // fp32 W2 (<=65536 floats), clear of udb & ymax
  float* ymax  = pd + (size_t)16*1024*1024;
  float* ymin  = pd + (size_t)21*1024*1024;
  // conv5 partials live in the pd region (dead after last k_apply): 16 slots per (b,o)
  float* pmax  = pd;
  float* pmin  = pd + (size_t)(1<<20);
  float* psum  = pd + (size_t)(2<<20);
  float* psq   = pd + (size_t)(3<<20);
  float* xt0   = ws + F_XT0;
  float* xc    = ws + F_XC;
  float* chsum = ws + F_CHS;
  float* chsq  = ws + F_CHQ;
  float* scl   = ws + F_SCL;
  float* shf   = ws + F_SHF;
  float* sqb   = ws + F_SQ;
  int*   idxb  = (int*)(ws + F_IDX);
  float* sc5   = ws + F_SC5;
  float* sh5   = ws + F_SH5;
  __hip_bfloat16* xcb = (__hip_bfloat16*)(ws + F_XCB);
  __hip_bfloat16* wb  = (__hip_bfloat16*)(ws + F_WB);
  __hip_bfloat16* w5b = wb + 32768;    // 1024x512
  _Float16* Ph  = (_Float16*)(ws + F_PH);
  _Float16* Pl  = (_Float16*)(ws + F_PL);

  (void)in_sizes; (void)n_in; (void)out_size; (void)ws_size;

  k_transpose<<<64, 256, 0, stream>>>(x, xt0);
  k_cvtw<<<(524288+255)/256, 256, 0, stream>>>(w5, w5b, 512, 0, 512, 512, 524288);

  struct LayerP { const float* P; int stride; int Ci; int CiD; int Cpad;
                  const float* W; const float* g; const float* b; int Oi; int off; };
  LayerP L[4] = {
    { xt0,    4,   3,   4,   32,  w1, g1, b1,  64, 0   },
    { xc,     512, 64,  64,  64,  w2, g2, b2,  64, 64  },
    { xc+64,  512, 64,  64,  64,  w3, g3, b3, 128, 128 },
    { xc+128, 512, 128, 128, 128, w4, g4, b4, 256, 256 },
  };

  for (int l=0; l<4; ++l){
    int Cpad = L[l].Cpad, nchunk = Cpad/32;
    int Oi = L[l].Oi, Ci = L[l].Ci;
    int ostr = 2*Oi;
    k_split<<<(BB*NN*Cpad+255)/256, 256, 0, stream>>>(L[l].P, L[l].stride, L[l].CiD, Cpad, Ph, Pl);
    k_sqs<<<64, 256, 0, stream>>>(Ph, Pl, Cpad, sqb);
    k_distm<<<dim3(16,16,8), 256, 0, stream>>>(Ph, Pl, Cpad, nchunk, sqb, pd);
    k_topk<<<BB*NN/4, 256, 0, stream>>>(pd, idxb);
    hipMemsetAsync(chsum, 0, (size_t)NSLOT*256*2*sizeof(float), stream);
    // pd is dead now: build W2 and the per-point U/D GEMM in its place (exact fp32)
    k_wprep<<<(2*Oi*Ci+255)/256, 256, 0, stream>>>(L[l].W, Ci, Oi, w2buf);
    k_gemmud<<<dim3(BB*NN/64, ostr/64), 256, 0, stream>>>(L[l].P, L[l].stride, Ci, w2buf, ostr, udb);
    k_edge<<<dim3(BB*NN/16, Oi/64), 256, 0, stream>>>(udb, ostr, Oi, idxb, ymax, ymin, chsum, chsq);
    k_bnstats<<<1, 256, 0, stream>>>(chsum, chsq, L[l].g, L[l].b, scl, shf, Oi);
    k_apply<<<(BB*NN*Oi + 255)/256, 256, 0, stream>>>(ymax, ymin, scl, shf, xc, xcb, L[l].off, Oi);
  }

  k_conv5m<<<dim3(16, 8, BB), 256, 0, stream>>>(xcb, w5b, pmax, pmin, psum, psq);
  k_stats5<<<4, 256, 0, stream>>>(psum, psq, g5, b5, sc5, sh5);
  k_apply5<<<(BB*1024)/256, 256, 0, stream>>>(pmax, pmin, sc5, sh5, out);
}

// Round 11
// 676.362 us; speedup vs baseline: 1.0797x; 1.0086x over previous
//
#include <hip/hip_runtime.h>
#include <hip/hip_bf16.h>
#include <math.h>

#define BB 8
#define NN 2048
#define KK 20
#define XCCH 512
#define NSLOT 64
#define LEPS 1e-5f
#define NEGINF -3.4e38f

typedef __attribute__((ext_vector_type(8))) short s8v;
typedef __attribute__((ext_vector_type(8))) _Float16 h8v;
typedef __attribute__((ext_vector_type(4))) float f32x4;

__device__ __forceinline__ float lrelu(float x){ return x >= 0.f ? x : 0.2f*x; }

// ---------- transpose x (B,3,N) -> xt0 (B*N,4) fp32 ----------
__global__ __launch_bounds__(256) void k_transpose(const float* __restrict__ x, float* __restrict__ xt){
  int i = blockIdx.x*256 + threadIdx.x;
  if (i >= BB*NN) return;
  int b = i >> 11, n = i & (NN-1);
  float4 v;
  v.x = x[(b*3+0)*NN + n];
  v.y = x[(b*3+1)*NN + n];
  v.z = x[(b*3+2)*NN + n];
  v.w = 0.f;
  reinterpret_cast<float4*>(xt)[i] = v;
}

// ---------- weight fp32 -> bf16 slice with K padding ----------
__global__ __launch_bounds__(256) void k_cvtw(const float* __restrict__ W, __hip_bfloat16* __restrict__ Wb,
                                              int Cs, int coff, int Ccnt, int Cpad, int total){
  int i = blockIdx.x*256 + threadIdx.x;
  if (i >= total) return;
  int o = i / Cpad, c = i - o*Cpad;
  Wb[i] = (c < Ccnt) ? __float2bfloat16(W[(size_t)o*Cs + coff + c]) : __float2bfloat16(0.f);
}

// ---------- split P fp32 -> hi/lo f16 (Cpad cols, zero-padded) ----------
__global__ __launch_bounds__(256) void k_split(const float* __restrict__ P, int stride, int Ci, int Cpad,
    _Float16* __restrict__ Ph, _Float16* __restrict__ Pl){
  int i = blockIdx.x*256 + threadIdx.x;
  if (i >= BB*NN*Cpad) return;
  int p = i / Cpad, c = i - p*Cpad;
  float v = (c < Ci) ? P[(size_t)p*stride + c] : 0.f;
  _Float16 h = (_Float16)v;
  float r = v - (float)h;
  Ph[i] = h;
  Pl[i] = (_Float16)r;
}

// ---------- squared norms from the split representation (consistent with k_distm) ----------
__global__ __launch_bounds__(256) void k_sqs(const _Float16* __restrict__ Ph,
    const _Float16* __restrict__ Pl, int Cpad, float* __restrict__ sq){
  int i = blockIdx.x*256 + threadIdx.x;
  if (i >= BB*NN) return;
  const _Float16* ph = Ph + (size_t)i*Cpad;
  const _Float16* pl = Pl + (size_t)i*Cpad;
  float s = 0.f;
  for (int c = 0; c < Cpad; ++c){
    float v = (float)ph[c] + (float)pl[c];
    s += v*v;
  }
  sq[i] = s;
}

// ---------- MFMA pairwise score, SYMMETRIC: only lower-triangle block pairs ----------
// blockIdx.x in [0,136): decode (bx,by) with bx <= by; n0 = by*128 (rows), m0 = bx*128 (cols).
// Off-diagonal blocks also write the mirrored tile (same dot, row-norm-first order).
__global__ __launch_bounds__(256) void k_distm(
    const _Float16* __restrict__ Ph, const _Float16* __restrict__ Pl,
    int Cpad, int nchunk, const float* __restrict__ sq, float* __restrict__ pd)
{
  __shared__ _Float16 Ah[128*40];
  __shared__ _Float16 Al[128*40];
  __shared__ _Float16 Bh[128*40];
  __shared__ _Float16 Bl[128*40];
  int t = threadIdx.x;
  int w = t >> 6, lane = t & 63, m = lane & 15, quad = lane >> 4;
  int b = blockIdx.z;
  int i = blockIdx.x;
  int by = (int)((sqrtf(8.f*(float)i + 1.f) - 1.f) * 0.5f);
  while ((by+1)*(by+2)/2 <= i) by++;
  while (by*(by+1)/2 > i) by--;
  int bx = i - by*(by+1)/2;           // bx <= by
  int n0 = by * 128, m0 = bx * 128;
  const _Float16* PhB = Ph + (size_t)b*NN*Cpad;
  const _Float16* PlB = Pl + (size_t)b*NN*Cpad;
  f32x4 acc[2][8];
  #pragma unroll
  for (int s=0;s<2;s++)
    #pragma unroll
    for (int j=0;j<8;j++){ f32x4 z = {0.f,0.f,0.f,0.f}; acc[s][j] = z; }
  int r = t >> 1;
  int sg0 = t & 1;
  for (int ch=0; ch<nchunk; ++ch){
    int c0 = ch*32;
    #pragma unroll
    for (int k=0;k<2;k++){
      int seg = sg0 + 2*k;
      int go = c0 + seg*8;
      size_t an = (size_t)(n0+r)*Cpad + go;
      size_t bm = (size_t)(m0+r)*Cpad + go;
      *(h8v*)&Ah[r*40 + seg*8] = *(const h8v*)&PhB[an];
      *(h8v*)&Al[r*40 + seg*8] = *(const h8v*)&PlB[an];
      *(h8v*)&Bh[r*40 + seg*8] = *(const h8v*)&PhB[bm];
      *(h8v*)&Bl[r*40 + seg*8] = *(const h8v*)&PlB[bm];
    }
    __syncthreads();
    h8v ah0 = *(const h8v*)&Ah[(w*32 + m)*40 + quad*8];
    h8v al0 = *(const h8v*)&Al[(w*32 + m)*40 + quad*8];
    h8v ah1 = *(const h8v*)&Ah[(w*32 + 16 + m)*40 + quad*8];
    h8v al1 = *(const h8v*)&Al[(w*32 + 16 + m)*40 + quad*8];
    #pragma unroll
    for (int j=0;j<8;j++){
      h8v bh = *(const h8v*)&Bh[(j*16 + m)*40 + quad*8];
      h8v bl = *(const h8v*)&Bl[(j*16 + m)*40 + quad*8];
      acc[0][j] = __builtin_amdgcn_mfma_f32_16x16x32_f16(ah0, bh, acc[0][j], 0, 0, 0);
      acc[0][j] = __builtin_amdgcn_mfma_f32_16x16x32_f16(ah0, bl, acc[0][j], 0, 0, 0);
      acc[0][j] = __builtin_amdgcn_mfma_f32_16x16x32_f16(al0, bh, acc[0][j], 0, 0, 0);
      acc[0][j] = __builtin_amdgcn_mfma_f32_16x16x32_f16(al0, bl, acc[0][j], 0, 0, 0);
      acc[1][j] = __builtin_amdgcn_mfma_f32_16x16x32_f16(ah1, bh, acc[1][j], 0, 0, 0);
      acc[1][j] = __builtin_amdgcn_mfma_f32_16x16x32_f16(ah1, bl, acc[1][j], 0, 0, 0);
      acc[1][j] = __builtin_amdgcn_mfma_f32_16x16x32_f16(al1, bh, acc[1][j], 0, 0, 0);
      acc[1][j] = __builtin_amdgcn_mfma_f32_16x16x32_f16(al1, bl, acc[1][j], 0, 0, 0);
    }
    __syncthreads();
  }
  float sqm_[8];
  #pragma unroll
  for (int j=0;j<8;j++) sqm_[j] = sq[b*NN + m0 + j*16 + m];
  float sqn_[2][4];
  #pragma unroll
  for (int s=0;s<2;s++)
    #pragma unroll
    for (int rg=0; rg<4; rg++)
      sqn_[s][rg] = sq[b*NN + n0 + w*32 + s*16 + quad*4 + rg];
  // normal tile: rows n, cols m (row-norm subtracted first, as baseline)
  #pragma unroll
  for (int s=0;s<2;s++){
    #pragma unroll
    for (int rg=0; rg<4; rg++){
      size_t rowoff = ((size_t)b*NN + n0 + w*32 + s*16 + quad*4 + rg)*NN + m0 + m;
      #pragma unroll
      for (int j=0;j<8;j++){
        pd[rowoff + j*16] = 2.f*acc[s][j][rg] - sqn_[s][rg] - sqm_[j];
      }
    }
  }
  // mirrored tile: rows m, cols n (row-norm = sqm first)
  if (bx != by){
    #pragma unroll
    for (int s=0;s<2;s++){
      #pragma unroll
      for (int j=0;j<8;j++){
        size_t moff = ((size_t)b*NN + m0 + j*16 + m)*NN + n0 + w*32 + s*16 + quad*4;
        float4 v;
        v.x = 2.f*acc[s][j][0] - sqm_[j] - sqn_[s][0];
        v.y = 2.f*acc[s][j][1] - sqm_[j] - sqn_[s][1];
        v.z = 2.f*acc[s][j][2] - sqm_[j] - sqn_[s][2];
        v.w = 2.f*acc[s][j][3] - sqm_[j] - sqn_[s][3];
        *(float4*)&pd[moff] = v;
      }
    }
  }
}

// ---------- top-20 per row: bulk extraction, lazy top-3 state (rescan only after 2 pops) ----------
#define TK_REP32(F) F(0)F(1)F(2)F(3)F(4)F(5)F(6)F(7)F(8)F(9)F(10)F(11)F(12)F(13)F(14)F(15) \
                    F(16)F(17)F(18)F(19)F(20)F(21)F(22)F(23)F(24)F(25)F(26)F(27)F(28)F(29)F(30)F(31)
// top-3 scan; ORDER MATTERS: p3(old p2), i2(old i1), p2(old p1), i1, p1
#define TK3_SCAN(u) { bool c1 = r##u > p1; bool c2 = r##u > p2; bool c3 = r##u > p3; \
    p3 = c2 ? p2 : (c3 ? r##u : p3); \
    i2 = c1 ? i1 : (c2 ? u : i2); \
    p2 = c1 ? p1 : (c2 ? r##u : p2); \
    i1 = c1 ? u : i1; \
    p1 = c1 ? r##u : p1; }
#define TK3_RSCAN(u) { float vv = ((rem >> u) & 1u) ? NEGINF : r##u; \
    bool c1 = vv > p1; bool c2 = vv > p2; bool c3 = vv > p3; \
    p3 = c2 ? p2 : (c3 ? vv : p3); \
    i2 = c1 ? i1 : (c2 ? u : i2); \
    p2 = c1 ? p1 : (c2 ? vv : p2); \
    i1 = c1 ? u : i1; \
    p1 = c1 ? vv : p1; }

__global__ __launch_bounds__(256) void k_topk(const float* __restrict__ pd, int* __restrict__ idxo){
  int t = threadIdx.x;
  int l = t & 63;
  int row = blockIdx.x*4 + (t >> 6);
  const float4* rp = (const float4*)(pd + (size_t)row*NN);
  float4 q0 = rp[0*64+l], q1 = rp[1*64+l], q2 = rp[2*64+l], q3 = rp[3*64+l];
  float4 q4 = rp[4*64+l], q5 = rp[5*64+l], q6 = rp[6*64+l], q7 = rp[7*64+l];
  float r0 =q0.x, r1 =q0.y, r2 =q0.z, r3 =q0.w, r4 =q1.x, r5 =q1.y, r6 =q1.z, r7 =q1.w;
  float r8 =q2.x, r9 =q2.y, r10=q2.z, r11=q2.w, r12=q3.x, r13=q3.y, r14=q3.z, r15=q3.w;
  float r16=q4.x, r17=q4.y, r18=q4.z, r19=q4.w, r20=q5.x, r21=q5.y, r22=q5.z, r23=q5.w;
  float r24=q6.x, r25=q6.y, r26=q6.z, r27=q6.w, r28=q7.x, r29=q7.y, r30=q7.z, r31=q7.w;
  float p1 = NEGINF, p2 = NEGINF, p3 = NEGINF;
  int i1 = 0, i2 = 0, nv = 3;
  unsigned rem = 0u;
  TK_REP32(TK3_SCAN)
  int* orow = idxo + (size_t)row*KK;
  int got = 0;
  while (got < KK){
    float M2 = p2;
    #pragma unroll
    for (int off=1; off<64; off<<=1) M2 = fmaxf(M2, __shfl_xor(M2, off));
    bool ex = (p1 >= M2);
    unsigned long long ball = __ballot(ex);
    int cnt = __popcll(ball);
    int take = KK - got;
    if (cnt <= take){
      if (ex){
        int pos = got + __popcll(ball & ((1ull << l) - 1ull));
        orow[pos] = ((i1 >> 2) << 8) | (l << 2) | (i1 & 3);
        rem |= 1u << i1;
        p1 = p2; i1 = i2; p2 = p3; nv--;
      }
      got += cnt;
      if (got < KK && nv < 2){
        p1 = NEGINF; p2 = NEGINF; p3 = NEGINF; i1 = 0; i2 = 0;
        TK_REP32(TK3_RSCAN)
        nv = 3;
      }
    } else {
      // remaining top-take are one-per-lane (the extracting p1s): no rescan needed
      for (int tt = 0; tt < take; ++tt){
        float wv = p1;
        #pragma unroll
        for (int off=1; off<64; off<<=1) wv = fmaxf(wv, __shfl_xor(wv, off));
        int gi = (p1 == wv) ? (((i1 >> 2) << 8) | (l << 2) | (i1 & 3)) : 0x7FFFFFFF;
        int cand = gi;
        #pragma unroll
        for (int off=1; off<64; off<<=1){
          int oc = __shfl_xor(cand, off);
          cand = oc < cand ? oc : cand;
        }
        if (gi == cand){
          orow[got + tt] = cand;
          p1 = NEGINF;
        }
      }
      got = KK;
    }
  }
}

// ---------- build W2 (2*Oi x Ci) fp32: rows [0,Oi) = W_diff, rows [Oi,2Oi) = W_ctr - W_diff ----------
__global__ __launch_bounds__(256) void k_wprep(const float* __restrict__ W, int Ci, int Oi,
                                               float* __restrict__ W2){
  int i = blockIdx.x*256 + threadIdx.x;
  if (i >= 2*Oi*Ci) return;
  int r = i / Ci, c = i - r*Ci;
  if (r < Oi){
    W2[i] = W[(size_t)r*2*Ci + Ci + c];
  } else {
    int o = r - Oi;
    W2[i] = W[(size_t)o*2*Ci + c] - W[(size_t)o*2*Ci + Ci + c];
  }
}

// ---------- U/D GEMM fp32 (exact): 64x64 tile, transposed LDS, b128 reads ----------
__global__ __launch_bounds__(256) void k_gemmud(const float* __restrict__ P, int stride, int Ci,
    const float* __restrict__ W2, int ostr, float* __restrict__ udb){
  __shared__ float Pt[16*68];
  __shared__ float Wt[16*68];
  int t = threadIdx.x, ty = t >> 4, tx = t & 15;
  int p0 = blockIdx.x*64, o0 = blockIdx.y*64;
  float acc[4][4];
  #pragma unroll
  for (int i=0;i<4;i++)
    #pragma unroll
    for (int j=0;j<4;j++) acc[i][j]=0.f;
  for (int c0 = 0; c0 < Ci; c0 += 16){
    #pragma unroll
    for (int q=0;q<4;q++){
      int e = t + 256*q;
      int r = e >> 4, cc = e & 15;
      int c = c0 + cc;
      bool ok = (c < Ci);
      Pt[cc*68 + r] = ok ? P[(size_t)(p0+r)*stride + c] : 0.f;
      Wt[cc*68 + r] = ok ? W2[(size_t)(o0+r)*Ci + c] : 0.f;
    }
    __syncthreads();
    #pragma unroll
    for (int j=0;j<16;j++){
      float4 av  = *(const float4*)&Pt[j*68 + ty*4];
      float4 bv4 = *(const float4*)&Wt[j*68 + tx*4];
      float a[4]  = {av.x, av.y, av.z, av.w};
      float bv[4] = {bv4.x, bv4.y, bv4.z, bv4.w};
      #pragma unroll
      for (int i=0;i<4;i++)
        #pragma unroll
        for (int jj=0;jj<4;jj++) acc[i][jj] += a[i]*bv[jj];
    }
    __syncthreads();
  }
  #pragma unroll
  for (int i=0;i<4;i++){
    *(float4*)&udb[(size_t)(p0+ty*4+i)*ostr + o0 + tx*4] =
      make_float4(acc[i][0], acc[i][1], acc[i][2], acc[i][3]);
  }
}

// ---------- edge gather-reduce: y[n,k,o] = U[nbr(n,k),o] + D[n,o] ----------
__global__ __launch_bounds__(256) void k_edge(const float* __restrict__ udb, int ostr, int Oi,
    const int* __restrict__ idxg,
    float* __restrict__ ymax, float* __restrict__ ymin,
    float* __restrict__ chsum, float* __restrict__ chsq){
  __shared__ int lidx[16*KK];
  __shared__ float reds[2][4][64];
  int t = threadIdx.x, w = t >> 6, lane = t & 63;
  int n0 = blockIdx.x*16;
  int b  = n0 >> 11;
  int o0 = blockIdx.y*64;
  for (int q=t; q<16*KK; q+=256) lidx[q] = idxg[(size_t)n0*KK + q];
  __syncthreads();
  int o = o0 + lane;
  float ws_s = 0.f, ws_q = 0.f;
  #pragma unroll
  for (int p=0;p<4;p++){
    int pl = w*4 + p;
    int n = n0 + pl;
    float mx = -3.4e38f, mn = 3.4e38f, s = 0.f, s2 = 0.f;
    #pragma unroll
    for (int k=0;k<KK;k++){
      int nb = lidx[pl*KK + k];
      float u = udb[(size_t)((b<<11) + nb)*ostr + o];
      mx = fmaxf(mx, u); mn = fminf(mn, u);
      s += u; s2 += u*u;
    }
    float Dv = udb[(size_t)n*ostr + Oi + o];
    size_t base = (size_t)n*256 + o;
    ymax[base] = mx + Dv;
    ymin[base] = mn + Dv;
    ws_s += s + (float)KK*Dv;
    ws_q += s2 + 2.f*Dv*s + (float)KK*Dv*Dv;
  }
  reds[0][w][lane] = ws_s;
  reds[1][w][lane] = ws_q;
  __syncthreads();
  if (w == 0){
    float s = reds[0][0][lane] + reds[0][1][lane] + reds[0][2][lane] + reds[0][3][lane];
    float q = reds[1][0][lane] + reds[1][1][lane] + reds[1][2][lane] + reds[1][3][lane];
    int slot = blockIdx.x & (NSLOT-1);
    atomicAdd(&chsum[slot*256 + o], s);
    atomicAdd(&chsq [slot*256 + o], q);
  }
}

// ---------- BN stats finalize ----------
__global__ __launch_bounds__(256) void k_bnstats(const float* __restrict__ chsum, const float* __restrict__ chsq,
    const float* __restrict__ g, const float* __restrict__ bet,
    float* __restrict__ scl, float* __restrict__ shf, int Oi){
  int o = threadIdx.x;
  if (o >= Oi) return;
  float s=0.f, s2=0.f;
  for (int u=0;u<NSLOT;u++){ s += chsum[u*256+o]; s2 += chsq[u*256+o]; }
  float cnt = (float)(BB*NN*KK);
  float mean = s/cnt;
  float var = s2/cnt - mean*mean;
  float sc = g[o] / sqrtf(var + LEPS);
  scl[o] = sc;
  shf[o] = bet[o] - mean*sc;
}

// ---------- apply BN+LReLU, write fp32 xc + bf16 xcb ----------
__global__ __launch_bounds__(256) void k_apply(const float* __restrict__ ymax, const float* __restrict__ ymin,
    const float* __restrict__ scl, const float* __restrict__ shf,
    float* __restrict__ xc, __hip_bfloat16* __restrict__ xcb, int off, int Oi){
  int i = blockIdx.x*256 + threadIdx.x;
  if (i >= BB*NN*Oi) return;
  int o = i & (Oi-1);
  size_t p = (size_t)((unsigned)i / (unsigned)Oi);
  float sc = scl[o];
  float v = (sc >= 0.f) ? ymax[p*256+o] : ymin[p*256+o];
  float r = lrelu(v*sc + shf[o]);
  xc [p*XCCH + off + o] = r;
  xcb[p*XCCH + off + o] = __float2bfloat16(r);
}

// ---------- MFMA conv5: 128 pts x 128 outs per block, LDS-staged, fused stats epilogue ----------
__global__ __launch_bounds__(256) void k_conv5m(const __hip_bfloat16* __restrict__ xcb,
    const __hip_bfloat16* __restrict__ w5b,
    float* __restrict__ pmax, float* __restrict__ pmin,
    float* __restrict__ psum, float* __restrict__ psq)
{
  __shared__ __align__(16) char smem[20480];
  __hip_bfloat16* As = (__hip_bfloat16*)smem;
  __hip_bfloat16* Bs = (__hip_bfloat16*)(smem + 10240);
  float* red = (float*)smem;
  int t = threadIdx.x, w = t >> 6, lane = t & 63, m = lane & 15, quad = lane >> 4;
  int nbk = blockIdx.x;
  int b = blockIdx.z;
  int o0 = blockIdx.y * 128;
  int n0 = nbk * 128;
  const __hip_bfloat16* Abase = xcb + (size_t)(b*NN + n0)*XCCH;
  const __hip_bfloat16* Bbase = w5b + (size_t)o0*XCCH;
  f32x4 acc[2][8];
  #pragma unroll
  for (int s=0;s<2;s++)
    #pragma unroll
    for (int j=0;j<8;j++){ f32x4 z = {0.f,0.f,0.f,0.f}; acc[s][j] = z; }
  int r = t >> 1;
  int sg0 = t & 1;
  for (int ch=0; ch<16; ++ch){
    int c0 = ch*32;
    #pragma unroll
    for (int k=0;k<2;k++){
      int seg = sg0 + 2*k;
      int go = c0 + seg*8;
      *(s8v*)&As[r*40 + seg*8] = *(const s8v*)&Abase[(size_t)r*XCCH + go];
      *(s8v*)&Bs[r*40 + seg*8] = *(const s8v*)&Bbase[(size_t)r*XCCH + go];
    }
    __syncthreads();
    s8v a0 = *(const s8v*)&As[(w*32 + m)*40 + quad*8];
    s8v a1 = *(const s8v*)&As[(w*32 + 16 + m)*40 + quad*8];
    #pragma unroll
    for (int j=0;j<8;j++){
      s8v bf = *(const s8v*)&Bs[(j*16 + m)*40 + quad*8];
      acc[0][j] = __builtin_amdgcn_mfma_f32_16x16x32_bf16(a0, bf, acc[0][j], 0, 0, 0);
      acc[1][j] = __builtin_amdgcn_mfma_f32_16x16x32_bf16(a1, bf, acc[1][j], 0, 0, 0);
    }
    __syncthreads();
  }
  float mx[8], mn[8], sm[8], sq[8];
  #pragma unroll
  for (int j=0;j<8;j++){
    mx[j] = -3.4e38f; mn[j] = 3.4e38f; sm[j] = 0.f; sq[j] = 0.f;
    #pragma unroll
    for (int s=0;s<2;s++){
      f32x4 a = acc[s][j];
      #pragma unroll
      for (int rg=0; rg<4; rg++){
        float v = a[rg];
        mx[j] = fmaxf(mx[j], v); mn[j] = fminf(mn[j], v);
        sm[j] += v; sq[j] += v*v;
      }
    }
  }
  #pragma unroll
  for (int j=0;j<8;j++){
    #pragma unroll
    for (int off=16; off<=32; off<<=1){
      mx[j] = fmaxf(mx[j], __shfl_xor(mx[j], off));
      mn[j] = fminf(mn[j], __shfl_xor(mn[j], off));
      sm[j] += __shfl_xor(sm[j], off);
      sq[j] += __shfl_xor(sq[j], off);
    }
  }
  if (quad == 0){
    #pragma unroll
    for (int j=0;j<8;j++){
      int c = j*16 + m;
      red[(0*4 + w)*128 + c] = mx[j];
      red[(1*4 + w)*128 + c] = mn[j];
      red[(2*4 + w)*128 + c] = sm[j];
      red[(3*4 + w)*128 + c] = sq[j];
    }
  }
  __syncthreads();
  if (t < 128){
    int c = t;
    float MX = red[(0*4+0)*128+c], MN = red[(1*4+0)*128+c];
    float S  = red[(2*4+0)*128+c], Q  = red[(3*4+0)*128+c];
    #pragma unroll
    for (int u=1;u<4;u++){
      MX = fmaxf(MX, red[(0*4+u)*128+c]);
      MN = fminf(MN, red[(1*4+u)*128+c]);
      S += red[(2*4+u)*128+c];
      Q += red[(3*4+u)*128+c];
    }
    size_t ii = ((size_t)b*1024 + o0 + c)*16 + nbk;
    pmax[ii] = MX; pmin[ii] = MN; psum[ii] = S; psq[ii] = Q;
  }
}

__global__ __launch_bounds__(256) void k_stats5(const float* __restrict__ psum, const float* __restrict__ psq,
    const float* __restrict__ g5, const float* __restrict__ b5,
    float* __restrict__ sc5, float* __restrict__ sh5){
  int o = blockIdx.x*256 + threadIdx.x;
  float s=0.f, s2=0.f;
  for (int b=0;b<BB;b++){
    const float* ps = &psum[((size_t)b*1024 + o)*16];
    const float* pq = &psq [((size_t)b*1024 + o)*16];
    #pragma unroll
    for (int u=0;u<16;u++){ s += ps[u]; s2 += pq[u]; }
  }
  float cnt = (float)(BB*NN);
  float mean = s/cnt;
  float var = s2/cnt - mean*mean;
  float sc = g5[o] / sqrtf(var + LEPS);
  sc5[o] = sc;
  sh5[o] = b5[o] - mean*sc;
}

__global__ __launch_bounds__(256) void k_apply5(const float* __restrict__ pmax, const float* __restrict__ pmin,
    const float* __restrict__ sc5, const float* __restrict__ sh5, float* __restrict__ out){
  int i = blockIdx.x*256 + threadIdx.x;
  int o = i & 1023;
  float sc = sc5[o];
  float v;
  if (sc >= 0.f){
    const float* p = &pmax[(size_t)i*16];
    v = p[0];
    #pragma unroll
    for (int u=1;u<16;u++) v = fmaxf(v, p[u]);
  } else {
    const float* p = &pmin[(size_t)i*16];
    v = p[0];
    #pragma unroll
    for (int u=1;u<16;u++) v = fminf(v, p[u]);
  }
  out[i] = lrelu(v*sc + sh5[o]);
}

extern "C" void kernel_launch(void* const* d_in, const int* in_sizes, int n_in,
                              void* d_out, int out_size, void* d_ws, size_t ws_size,
                              hipStream_t stream){
  const float* x  = (const float*)d_in[0];
  const float* w1 = (const float*)d_in[1];
  const float* g1 = (const float*)d_in[2];
  const float* b1 = (const float*)d_in[3];
  const float* w2 = (const float*)d_in[4];
  const float* g2 = (const float*)d_in[5];
  const float* b2 = (const float*)d_in[6];
  const float* w3 = (const float*)d_in[7];
  const float* g3 = (const float*)d_in[8];
  const float* b3 = (const float*)d_in[9];
  const float* w4 = (const float*)d_in[10];
  const float* g4 = (const float*)d_in[11];
  const float* b4 = (const float*)d_in[12];
  const float* w5 = (const float*)d_in[13];
  const float* g5 = (const float*)d_in[14];
  const float* b5 = (const float*)d_in[15];
  float* out = (float*)d_out;
  float* ws = (float*)d_ws;

  const size_t F_PD   = 0;
  const size_t F_XT0  = F_PD   + (size_t)BB*NN*NN;
  const size_t F_XC   = F_XT0  + (size_t)BB*NN*4;
  const size_t F_CHS  = F_XC   + (size_t)BB*NN*XCCH;
  const size_t F_CHQ  = F_CHS  + (size_t)NSLOT*256;
  const size_t F_SCL  = F_CHQ  + (size_t)NSLOT*256;
  const size_t F_SHF  = F_SCL  + 256;
  const size_t F_SQ   = F_SHF  + 256;
  const size_t F_IDX  = F_SQ   + (size_t)BB*NN;
  const size_t F_PMAX = F_IDX  + (size_t)BB*NN*KK;
  const size_t F_PMIN = F_PMAX + (size_t)BB*1024*8;
  const size_t F_PSUM = F_PMIN + (size_t)BB*1024*8;
  const size_t F_PSQ  = F_PSUM + (size_t)BB*1024*8;
  const size_t F_SC5  = F_PSQ  + (size_t)BB*1024*8;
  const size_t F_SH5  = F_SC5  + 1024;
  const size_t F_XCB  = F_SH5  + 1024;
  const size_t F_WB   = F_XCB  + (size_t)BB*NN*XCCH/2;      // wb region (bf16)
  const size_t F_PH   = F_WB   + 278528;                    // Ph: BB*NN*128 f16 = 1048576 floats
  const size_t F_PL   = F_PH   + 1048576;

  float* pd    = ws + F_PD;
  float* udb   = pd;                          // alias pd (pd dead after k_topk); <=8.4M floats
  float* w2buf = pd + (size_t)12*1024*1024;   // fp32 W2 (<=65536 floats), clear of udb & ymax
  float* ymax  = pd + (size_t)16*1024*1024;
  float* ymin  = pd + (size_t)21*1024*1024;
  // conv5 partials live in the pd region (dead after last k_apply): 16 slots per (b,o)
  float* pmax  = pd;
  float* pmin  = pd + (size_t)(1<<20);
  float* psum  = pd + (size_t)(2<<20);
  float* psq   = pd + (size_t)(3<<20);
  float* xt0   = ws + F_XT0;
  float* xc    = ws + F_XC;
  float* chsum = ws + F_CHS;
  float* chsq  = ws + F_CHQ;
  float* scl   = ws + F_SCL;
  float* shf   = ws + F_SHF;
  float* sqb   = ws + F_SQ;
  int*   idxb  = (int*)(ws + F_IDX);
  float* sc5   = ws + F_SC5;
  float* sh5   = ws + F_SH5;
  __hip_bfloat16* xcb = (__hip_bfloat16*)(ws + F_XCB);
  __hip_bfloat16* wb  = (__hip_bfloat16*)(ws + F_WB);
  __hip_bfloat16* w5b = wb + 32768;    // 1024x512
  _Float16* Ph  = (_Float16*)(ws + F_PH);
  _Float16* Pl  = (_Float16*)(ws + F_PL);

  (void)in_sizes; (void)n_in; (void)out_size; (void)ws_size;

  k_transpose<<<64, 256, 0, stream>>>(x, xt0);
  k_cvtw<<<(524288+255)/256, 256, 0, stream>>>(w5, w5b, 512, 0, 512, 512, 524288);

  struct LayerP { const float* P; int stride; int Ci; int CiD; int Cpad;
                  const float* W; const float* g; const float* b; int Oi; int off; };
  LayerP L[4] = {
    { xt0,    4,   3,   4,   32,  w1, g1, b1,  64, 0   },
    { xc,     512, 64,  64,  64,  w2, g2, b2,  64, 64  },
    { xc+64,  512, 64,  64,  64,  w3, g3, b3, 128, 128 },
    { xc+128, 512, 128, 128, 128, w4, g4, b4, 256, 256 },
  };

  for (int l=0; l<4; ++l){
    int Cpad = L[l].Cpad, nchunk = Cpad/32;
    int Oi = L[l].Oi, Ci = L[l].Ci;
    int ostr = 2*Oi;
    k_split<<<(BB*NN*Cpad+255)/256, 256, 0, stream>>>(L[l].P, L[l].stride, L[l].CiD, Cpad, Ph, Pl);
    k_sqs<<<64, 256, 0, stream>>>(Ph, Pl, Cpad, sqb);
    k_distm<<<dim3(136,1,8), 256, 0, stream>>>(Ph, Pl, Cpad, nchunk, sqb, pd);
    k_topk<<<BB*NN/4, 256, 0, stream>>>(pd, idxb);
    hipMemsetAsync(chsum, 0, (size_t)NSLOT*256*2*sizeof(float), stream);
    // pd is dead now: build W2 and the per-point U/D GEMM in its place (exact fp32)
    k_wprep<<<(2*Oi*Ci+255)/256, 256, 0, stream>>>(L[l].W, Ci, Oi, w2buf);
    k_gemmud<<<dim3(BB*NN/64, ostr/64), 256, 0, stream>>>(L[l].P, L[l].stride, Ci, w2buf, ostr, udb);
    k_edge<<<dim3(BB*NN/16, Oi/64), 256, 0, stream>>>(udb, ostr, Oi, idxb, ymax, ymin, chsum, chsq);
    k_bnstats<<<1, 256, 0, stream>>>(chsum, chsq, L[l].g, L[l].b, scl, shf, Oi);
    k_apply<<<(BB*NN*Oi + 255)/256, 256, 0, stream>>>(ymax, ymin, scl, shf, xc, xcb, L[l].off, Oi);
  }

  k_conv5m<<<dim3(16, 8, BB), 256, 0, stream>>>(xcb, w5b, pmax, pmin, psum, psq);
  k_stats5<<<4, 256, 0, stream>>>(psum, psq, g5, b5, sc5, sh5);
  k_apply5<<<(BB*1024)/256, 256, 0, stream>>>(pmax, pmin, sc5, sh5, out);
}

// Round 13
// 646.411 us; speedup vs baseline: 1.1297x; 1.0463x over previous
//
#include <hip/hip_runtime.h>
#include <hip/hip_bf16.h>
#include <math.h>

#define BB 8
#define NN 2048
#define KK 20
#define XCCH 512
#define NSLOT 64
#define LEPS 1e-5f
#define NEGINF -3.4e38f

typedef __attribute__((ext_vector_type(8))) short s8v;
typedef __attribute__((ext_vector_type(8))) _Float16 h8v;
typedef __attribute__((ext_vector_type(4))) float f32x4;

__device__ __forceinline__ float lrelu(float x){ return x >= 0.f ? x : 0.2f*x; }

// ---------- transpose x (B,3,N) -> xt0 (B*N,4) fp32 ----------
__global__ __launch_bounds__(256) void k_transpose(const float* __restrict__ x, float* __restrict__ xt){
  int i = blockIdx.x*256 + threadIdx.x;
  if (i >= BB*NN) return;
  int b = i >> 11, n = i & (NN-1);
  float4 v;
  v.x = x[(b*3+0)*NN + n];
  v.y = x[(b*3+1)*NN + n];
  v.z = x[(b*3+2)*NN + n];
  v.w = 0.f;
  reinterpret_cast<float4*>(xt)[i] = v;
}

// ---------- weight fp32 -> bf16 slice with K padding ----------
__global__ __launch_bounds__(256) void k_cvtw(const float* __restrict__ W, __hip_bfloat16* __restrict__ Wb,
                                              int Cs, int coff, int Ccnt, int Cpad, int total){
  int i = blockIdx.x*256 + threadIdx.x;
  if (i >= total) return;
  int o = i / Cpad, c = i - o*Cpad;
  Wb[i] = (c < Ccnt) ? __float2bfloat16(W[(size_t)o*Cs + coff + c]) : __float2bfloat16(0.f);
}

// ---------- split P fp32 -> hi/lo f16 (Cpad cols, zero-padded); used only for layer 1 (xt0) ----------
__global__ __launch_bounds__(256) void k_split(const float* __restrict__ P, int stride, int Ci, int Cpad,
    _Float16* __restrict__ Ph, _Float16* __restrict__ Pl){
  int i = blockIdx.x*256 + threadIdx.x;
  if (i >= BB*NN*Cpad) return;
  int p = i / Cpad, c = i - p*Cpad;
  float v = (c < Ci) ? P[(size_t)p*stride + c] : 0.f;
  _Float16 h = (_Float16)v;
  float r = v - (float)h;
  Ph[i] = h;
  Pl[i] = (_Float16)r;
}

// ---------- squared norms from the split representation (consistent with k_distm) ----------
__global__ __launch_bounds__(256) void k_sqs(const _Float16* __restrict__ Ph,
    const _Float16* __restrict__ Pl, int Cpad, float* __restrict__ sq){
  int i = blockIdx.x*256 + threadIdx.x;
  if (i >= BB*NN) return;
  const _Float16* ph = Ph + (size_t)i*Cpad;
  const _Float16* pl = Pl + (size_t)i*Cpad;
  float s = 0.f;
  for (int c = 0; c < Cpad; ++c){
    float v = (float)ph[c] + (float)pl[c];
    s += v*v;
  }
  sq[i] = s;
}

// ---------- MFMA pairwise score, SYMMETRIC: only lower-triangle block pairs ----------
__global__ __launch_bounds__(256) void k_distm(
    const _Float16* __restrict__ Ph, const _Float16* __restrict__ Pl,
    int Cpad, int nchunk, const float* __restrict__ sq, float* __restrict__ pd)
{
  __shared__ _Float16 Ah[128*40];
  __shared__ _Float16 Al[128*40];
  __shared__ _Float16 Bh[128*40];
  __shared__ _Float16 Bl[128*40];
  int t = threadIdx.x;
  int w = t >> 6, lane = t & 63, m = lane & 15, quad = lane >> 4;
  int b = blockIdx.z;
  int i = blockIdx.x;
  int by = (int)((sqrtf(8.f*(float)i + 1.f) - 1.f) * 0.5f);
  while ((by+1)*(by+2)/2 <= i) by++;
  while (by*(by+1)/2 > i) by--;
  int bx = i - by*(by+1)/2;           // bx <= by
  int n0 = by * 128, m0 = bx * 128;
  const _Float16* PhB = Ph + (size_t)b*NN*Cpad;
  const _Float16* PlB = Pl + (size_t)b*NN*Cpad;
  f32x4 acc[2][8];
  #pragma unroll
  for (int s=0;s<2;s++)
    #pragma unroll
    for (int j=0;j<8;j++){ f32x4 z = {0.f,0.f,0.f,0.f}; acc[s][j] = z; }
  int r = t >> 1;
  int sg0 = t & 1;
  for (int ch=0; ch<nchunk; ++ch){
    int c0 = ch*32;
    #pragma unroll
    for (int k=0;k<2;k++){
      int seg = sg0 + 2*k;
      int go = c0 + seg*8;
      size_t an = (size_t)(n0+r)*Cpad + go;
      size_t bm = (size_t)(m0+r)*Cpad + go;
      *(h8v*)&Ah[r*40 + seg*8] = *(const h8v*)&PhB[an];
      *(h8v*)&Al[r*40 + seg*8] = *(const h8v*)&PlB[an];
      *(h8v*)&Bh[r*40 + seg*8] = *(const h8v*)&PhB[bm];
      *(h8v*)&Bl[r*40 + seg*8] = *(const h8v*)&PlB[bm];
    }
    __syncthreads();
    h8v ah0 = *(const h8v*)&Ah[(w*32 + m)*40 + quad*8];
    h8v al0 = *(const h8v*)&Al[(w*32 + m)*40 + quad*8];
    h8v ah1 = *(const h8v*)&Ah[(w*32 + 16 + m)*40 + quad*8];
    h8v al1 = *(const h8v*)&Al[(w*32 + 16 + m)*40 + quad*8];
    #pragma unroll
    for (int j=0;j<8;j++){
      h8v bh = *(const h8v*)&Bh[(j*16 + m)*40 + quad*8];
      h8v bl = *(const h8v*)&Bl[(j*16 + m)*40 + quad*8];
      acc[0][j] = __builtin_amdgcn_mfma_f32_16x16x32_f16(ah0, bh, acc[0][j], 0, 0, 0);
      acc[0][j] = __builtin_amdgcn_mfma_f32_16x16x32_f16(ah0, bl, acc[0][j], 0, 0, 0);
      acc[0][j] = __builtin_amdgcn_mfma_f32_16x16x32_f16(al0, bh, acc[0][j], 0, 0, 0);
      acc[0][j] = __builtin_amdgcn_mfma_f32_16x16x32_f16(al0, bl, acc[0][j], 0, 0, 0);
      acc[1][j] = __builtin_amdgcn_mfma_f32_16x16x32_f16(ah1, bh, acc[1][j], 0, 0, 0);
      acc[1][j] = __builtin_amdgcn_mfma_f32_16x16x32_f16(ah1, bl, acc[1][j], 0, 0, 0);
      acc[1][j] = __builtin_amdgcn_mfma_f32_16x16x32_f16(al1, bh, acc[1][j], 0, 0, 0);
      acc[1][j] = __builtin_amdgcn_mfma_f32_16x16x32_f16(al1, bl, acc[1][j], 0, 0, 0);
    }
    __syncthreads();
  }
  float sqm_[8];
  #pragma unroll
  for (int j=0;j<8;j++) sqm_[j] = sq[b*NN + m0 + j*16 + m];
  float sqn_[2][4];
  #pragma unroll
  for (int s=0;s<2;s++)
    #pragma unroll
    for (int rg=0; rg<4; rg++)
      sqn_[s][rg] = sq[b*NN + n0 + w*32 + s*16 + quad*4 + rg];
  #pragma unroll
  for (int s=0;s<2;s++){
    #pragma unroll
    for (int rg=0; rg<4; rg++){
      size_t rowoff = ((size_t)b*NN + n0 + w*32 + s*16 + quad*4 + rg)*NN + m0 + m;
      #pragma unroll
      for (int j=0;j<8;j++){
        pd[rowoff + j*16] = 2.f*acc[s][j][rg] - sqn_[s][rg] - sqm_[j];
      }
    }
  }
  if (bx != by){
    #pragma unroll
    for (int s=0;s<2;s++){
      #pragma unroll
      for (int j=0;j<8;j++){
        size_t moff = ((size_t)b*NN + m0 + j*16 + m)*NN + n0 + w*32 + s*16 + quad*4;
        float4 v;
        v.x = 2.f*acc[s][j][0] - sqm_[j] - sqn_[s][0];
        v.y = 2.f*acc[s][j][1] - sqm_[j] - sqn_[s][1];
        v.z = 2.f*acc[s][j][2] - sqm_[j] - sqn_[s][2];
        v.w = 2.f*acc[s][j][3] - sqm_[j] - sqn_[s][3];
        *(float4*)&pd[moff] = v;
      }
    }
  }
}

// ---------- top-20 per row: bulk extraction, lazy top-3 state (rescan only after 2 pops) ----------
#define TK_REP32(F) F(0)F(1)F(2)F(3)F(4)F(5)F(6)F(7)F(8)F(9)F(10)F(11)F(12)F(13)F(14)F(15) \
                    F(16)F(17)F(18)F(19)F(20)F(21)F(22)F(23)F(24)F(25)F(26)F(27)F(28)F(29)F(30)F(31)
#define TK3_SCAN(u) { bool c1 = r##u > p1; bool c2 = r##u > p2; bool c3 = r##u > p3; \
    p3 = c2 ? p2 : (c3 ? r##u : p3); \
    i2 = c1 ? i1 : (c2 ? u : i2); \
    p2 = c1 ? p1 : (c2 ? r##u : p2); \
    i1 = c1 ? u : i1; \
    p1 = c1 ? r##u : p1; }
#define TK3_RSCAN(u) { float vv = ((rem >> u) & 1u) ? NEGINF : r##u; \
    bool c1 = vv > p1; bool c2 = vv > p2; bool c3 = vv > p3; \
    p3 = c2 ? p2 : (c3 ? vv : p3); \
    i2 = c1 ? i1 : (c2 ? u : i2); \
    p2 = c1 ? p1 : (c2 ? vv : p2); \
    i1 = c1 ? u : i1; \
    p1 = c1 ? vv : p1; }

__global__ __launch_bounds__(256) void k_topk(const float* __restrict__ pd, int* __restrict__ idxo){
  int t = threadIdx.x;
  int l = t & 63;
  int row = blockIdx.x*4 + (t >> 6);
  const float4* rp = (const float4*)(pd + (size_t)row*NN);
  float4 q0 = rp[0*64+l], q1 = rp[1*64+l], q2 = rp[2*64+l], q3 = rp[3*64+l];
  float4 q4 = rp[4*64+l], q5 = rp[5*64+l], q6 = rp[6*64+l], q7 = rp[7*64+l];
  float r0 =q0.x, r1 =q0.y, r2 =q0.z, r3 =q0.w, r4 =q1.x, r5 =q1.y, r6 =q1.z, r7 =q1.w;
  float r8 =q2.x, r9 =q2.y, r10=q2.z, r11=q2.w, r12=q3.x, r13=q3.y, r14=q3.z, r15=q3.w;
  float r16=q4.x, r17=q4.y, r18=q4.z, r19=q4.w, r20=q5.x, r21=q5.y, r22=q5.z, r23=q5.w;
  float r24=q6.x, r25=q6.y, r26=q6.z, r27=q6.w, r28=q7.x, r29=q7.y, r30=q7.z, r31=q7.w;
  float p1 = NEGINF, p2 = NEGINF, p3 = NEGINF;
  int i1 = 0, i2 = 0, nv = 3;
  unsigned rem = 0u;
  TK_REP32(TK3_SCAN)
  int* orow = idxo + (size_t)row*KK;
  int got = 0;
  while (got < KK){
    float M2 = p2;
    #pragma unroll
    for (int off=1; off<64; off<<=1) M2 = fmaxf(M2, __shfl_xor(M2, off));
    bool ex = (p1 >= M2);
    unsigned long long ball = __ballot(ex);
    int cnt = __popcll(ball);
    int take = KK - got;
    if (cnt <= take){
      if (ex){
        int pos = got + __popcll(ball & ((1ull << l) - 1ull));
        orow[pos] = ((i1 >> 2) << 8) | (l << 2) | (i1 & 3);
        rem |= 1u << i1;
        p1 = p2; i1 = i2; p2 = p3; nv--;
      }
      got += cnt;
      if (got < KK && nv < 2){
        p1 = NEGINF; p2 = NEGINF; p3 = NEGINF; i1 = 0; i2 = 0;
        TK_REP32(TK3_RSCAN)
        nv = 3;
      }
    } else {
      for (int tt = 0; tt < take; ++tt){
        float wv = p1;
        #pragma unroll
        for (int off=1; off<64; off<<=1) wv = fmaxf(wv, __shfl_xor(wv, off));
        int gi = (p1 == wv) ? (((i1 >> 2) << 8) | (l << 2) | (i1 & 3)) : 0x7FFFFFFF;
        int cand = gi;
        #pragma unroll
        for (int off=1; off<64; off<<=1){
          int oc = __shfl_xor(cand, off);
          cand = oc < cand ? oc : cand;
        }
        if (gi == cand){
          orow[got + tt] = cand;
          p1 = NEGINF;
        }
      }
      got = KK;
    }
  }
}

// ---------- build W2 (2*Oi x Ci) fp32: rows [0,Oi) = W_diff, rows [Oi,2Oi) = W_ctr - W_diff ----------
__global__ __launch_bounds__(256) void k_wprep(const float* __restrict__ W, int Ci, int Oi,
                                               float* __restrict__ W2){
  int i = blockIdx.x*256 + threadIdx.x;
  if (i >= 2*Oi*Ci) return;
  int r = i / Ci, c = i - r*Ci;
  if (r < Oi){
    W2[i] = W[(size_t)r*2*Ci + Ci + c];
  } else {
    int o = r - Oi;
    W2[i] = W[(size_t)o*2*Ci + c] - W[(size_t)o*2*Ci + Ci + c];
  }
}

// ---------- U/D GEMM fp32 (exact): 64x64 tile, transposed LDS, b128 reads (layers 1-3) ----------
__global__ __launch_bounds__(256) void k_gemmud(const float* __restrict__ P, int stride, int Ci,
    const float* __restrict__ W2, int ostr, float* __restrict__ udb){
  __shared__ float Pt[16*68];
  __shared__ float Wt[16*68];
  int t = threadIdx.x, ty = t >> 4, tx = t & 15;
  int p0 = blockIdx.x*64, o0 = blockIdx.y*64;
  float acc[4][4];
  #pragma unroll
  for (int i=0;i<4;i++)
    #pragma unroll
    for (int j=0;j<4;j++) acc[i][j]=0.f;
  for (int c0 = 0; c0 < Ci; c0 += 16){
    #pragma unroll
    for (int q=0;q<4;q++){
      int e = t + 256*q;
      int r = e >> 4, cc = e & 15;
      int c = c0 + cc;
      bool ok = (c < Ci);
      Pt[cc*68 + r] = ok ? P[(size_t)(p0+r)*stride + c] : 0.f;
      Wt[cc*68 + r] = ok ? W2[(size_t)(o0+r)*Ci + c] : 0.f;
    }
    __syncthreads();
    #pragma unroll
    for (int j=0;j<16;j++){
      float4 av  = *(const float4*)&Pt[j*68 + ty*4];
      float4 bv4 = *(const float4*)&Wt[j*68 + tx*4];
      float a[4]  = {av.x, av.y, av.z, av.w};
      float bv[4] = {bv4.x, bv4.y, bv4.z, bv4.w};
      #pragma unroll
      for (int i=0;i<4;i++)
        #pragma unroll
        for (int jj=0;jj<4;jj++) acc[i][jj] += a[i]*bv[jj];
    }
    __syncthreads();
  }
  #pragma unroll
  for (int i=0;i<4;i++){
    *(float4*)&udb[(size_t)(p0+ty*4+i)*ostr + o0 + tx*4] =
      make_float4(acc[i][0], acc[i][1], acc[i][2], acc[i][3]);
  }
}

// ---------- split W2 (2*Oi x Cpad) f16 hi/lo (layer 4 only) ----------
__global__ __launch_bounds__(256) void k_wprep2(const float* __restrict__ W, int Ci, int Cpad, int Oi,
                                                _Float16* __restrict__ W2h, _Float16* __restrict__ W2l){
  int i = blockIdx.x*256 + threadIdx.x;
  if (i >= 2*Oi*Cpad) return;
  int rr = i / Cpad, c = i - rr*Cpad;
  float v = 0.f;
  if (c < Ci){
    if (rr < Oi) v = W[(size_t)rr*2*Ci + Ci + c];
    else { int o = rr - Oi; v = W[(size_t)o*2*Ci + c] - W[(size_t)o*2*Ci + Ci + c]; }
  }
  _Float16 h = (_Float16)v;
  W2h[i] = h;
  W2l[i] = (_Float16)(v - (float)h);
}

// ---------- U/D GEMM via MFMA f16-split (LAYER 4 ONLY: no downstream knn => continuous error) ----------
__global__ __launch_bounds__(256) void k_gemmudm(
    const _Float16* __restrict__ Ph, const _Float16* __restrict__ Pl,
    int Cpad, int nchunk,
    const _Float16* __restrict__ W2h, const _Float16* __restrict__ W2l,
    int ostr, float* __restrict__ udb)
{
  __shared__ _Float16 Ah[128*40];
  __shared__ _Float16 Al[128*40];
  __shared__ _Float16 Bh[128*40];
  __shared__ _Float16 Bl[128*40];
  int t = threadIdx.x;
  int w = t >> 6, lane = t & 63, m = lane & 15, quad = lane >> 4;
  int p0 = blockIdx.x * 128, o0 = blockIdx.y * 128;
  f32x4 acc[2][8];
  #pragma unroll
  for (int s=0;s<2;s++)
    #pragma unroll
    for (int j=0;j<8;j++){ f32x4 z = {0.f,0.f,0.f,0.f}; acc[s][j] = z; }
  int r = t >> 1;
  int sg0 = t & 1;
  for (int ch=0; ch<nchunk; ++ch){
    int c0 = ch*32;
    #pragma unroll
    for (int k=0;k<2;k++){
      int seg = sg0 + 2*k;
      int go = c0 + seg*8;
      size_t an = (size_t)(p0+r)*Cpad + go;
      size_t bm = (size_t)(o0+r)*Cpad + go;
      *(h8v*)&Ah[r*40 + seg*8] = *(const h8v*)&Ph[an];
      *(h8v*)&Al[r*40 + seg*8] = *(const h8v*)&Pl[an];
      *(h8v*)&Bh[r*40 + seg*8] = *(const h8v*)&W2h[bm];
      *(h8v*)&Bl[r*40 + seg*8] = *(const h8v*)&W2l[bm];
    }
    __syncthreads();
    h8v ah0 = *(const h8v*)&Ah[(w*32 + m)*40 + quad*8];
    h8v al0 = *(const h8v*)&Al[(w*32 + m)*40 + quad*8];
    h8v ah1 = *(const h8v*)&Ah[(w*32 + 16 + m)*40 + quad*8];
    h8v al1 = *(const h8v*)&Al[(w*32 + 16 + m)*40 + quad*8];
    #pragma unroll
    for (int j=0;j<8;j++){
      h8v bh = *(const h8v*)&Bh[(j*16 + m)*40 + quad*8];
      h8v bl = *(const h8v*)&Bl[(j*16 + m)*40 + quad*8];
      acc[0][j] = __builtin_amdgcn_mfma_f32_16x16x32_f16(ah0, bh, acc[0][j], 0, 0, 0);
      acc[0][j] = __builtin_amdgcn_mfma_f32_16x16x32_f16(ah0, bl, acc[0][j], 0, 0, 0);
      acc[0][j] = __builtin_amdgcn_mfma_f32_16x16x32_f16(al0, bh, acc[0][j], 0, 0, 0);
      acc[0][j] = __builtin_amdgcn_mfma_f32_16x16x32_f16(al0, bl, acc[0][j], 0, 0, 0);
      acc[1][j] = __builtin_amdgcn_mfma_f32_16x16x32_f16(ah1, bh, acc[1][j], 0, 0, 0);
      acc[1][j] = __builtin_amdgcn_mfma_f32_16x16x32_f16(ah1, bl, acc[1][j], 0, 0, 0);
      acc[1][j] = __builtin_amdgcn_mfma_f32_16x16x32_f16(al1, bh, acc[1][j], 0, 0, 0);
      acc[1][j] = __builtin_amdgcn_mfma_f32_16x16x32_f16(al1, bl, acc[1][j], 0, 0, 0);
    }
    __syncthreads();
  }
  #pragma unroll
  for (int s=0;s<2;s++){
    int rbase = w*32 + s*16 + quad*4;
    #pragma unroll
    for (int rg=0; rg<4; rg++){
      size_t rowoff = (size_t)(p0 + rbase + rg)*ostr + o0 + m;
      #pragma unroll
      for (int j=0;j<8;j++){
        udb[rowoff + j*16] = acc[s][j][rg];
      }
    }
  }
}

// ---------- edge gather-reduce: y[n,k,o] = U[nbr(n,k),o] + D[n,o] ----------
__global__ __launch_bounds__(256) void k_edge(const float* __restrict__ udb, int ostr, int Oi,
    const int* __restrict__ idxg,
    float* __restrict__ ymax, float* __restrict__ ymin,
    float* __restrict__ chsum, float* __restrict__ chsq){
  __shared__ int lidx[16*KK];
  __shared__ float reds[2][4][64];
  int t = threadIdx.x, w = t >> 6, lane = t & 63;
  int n0 = blockIdx.x*16;
  int b  = n0 >> 11;
  int o0 = blockIdx.y*64;
  for (int q=t; q<16*KK; q+=256) lidx[q] = idxg[(size_t)n0*KK + q];
  __syncthreads();
  int o = o0 + lane;
  float ws_s = 0.f, ws_q = 0.f;
  #pragma unroll
  for (int p=0;p<4;p++){
    int pl = w*4 + p;
    int n = n0 + pl;
    float mx = -3.4e38f, mn = 3.4e38f, s = 0.f, s2 = 0.f;
    #pragma unroll
    for (int k=0;k<KK;k++){
      int nb = lidx[pl*KK + k];
      float u = udb[(size_t)((b<<11) + nb)*ostr + o];
      mx = fmaxf(mx, u); mn = fminf(mn, u);
      s += u; s2 += u*u;
    }
    float Dv = udb[(size_t)n*ostr + Oi + o];
    size_t base = (size_t)n*256 + o;
    ymax[base] = mx + Dv;
    ymin[base] = mn + Dv;
    ws_s += s + (float)KK*Dv;
    ws_q += s2 + 2.f*Dv*s + (float)KK*Dv*Dv;
  }
  reds[0][w][lane] = ws_s;
  reds[1][w][lane] = ws_q;
  __syncthreads();
  if (w == 0){
    float s = reds[0][0][lane] + reds[0][1][lane] + reds[0][2][lane] + reds[0][3][lane];
    float q = reds[1][0][lane] + reds[1][1][lane] + reds[1][2][lane] + reds[1][3][lane];
    int slot = blockIdx.x & (NSLOT-1);
    atomicAdd(&chsum[slot*256 + o], s);
    atomicAdd(&chsq [slot*256 + o], q);
  }
}

// ---------- BN stats finalize ----------
__global__ __launch_bounds__(256) void k_bnstats(const float* __restrict__ chsum, const float* __restrict__ chsq,
    const float* __restrict__ g, const float* __restrict__ bet,
    float* __restrict__ scl, float* __restrict__ shf, int Oi){
  int o = threadIdx.x;
  if (o >= Oi) return;
  float s=0.f, s2=0.f;
  for (int u=0;u<NSLOT;u++){ s += chsum[u*256+o]; s2 += chsq[u*256+o]; }
  float cnt = (float)(BB*NN*KK);
  float mean = s/cnt;
  float var = s2/cnt - mean*mean;
  float sc = g[o] / sqrtf(var + LEPS);
  scl[o] = sc;
  shf[o] = bet[o] - mean*sc;
}

// ---------- apply BN+LReLU; write xc (opt), bf16 xcb, and next-layer split Ph/Pl (opt) ----------
__global__ __launch_bounds__(256) void k_apply(const float* __restrict__ ymax, const float* __restrict__ ymin,
    const float* __restrict__ scl, const float* __restrict__ shf,
    float* __restrict__ xc, __hip_bfloat16* __restrict__ xcb, int off, int Oi,
    _Float16* __restrict__ Phn, _Float16* __restrict__ Pln, int Cnext, int writeXc){
  int i = blockIdx.x*256 + threadIdx.x;
  if (i >= BB*NN*Oi) return;
  int o = i & (Oi-1);
  size_t p = (size_t)((unsigned)i / (unsigned)Oi);
  float sc = scl[o];
  float v = (sc >= 0.f) ? ymax[p*256+o] : ymin[p*256+o];
  float r = lrelu(v*sc + shf[o]);
  if (writeXc) xc[p*XCCH + off + o] = r;
  xcb[p*XCCH + off + o] = __float2bfloat16(r);
  if (Cnext){
    _Float16 h = (_Float16)r;
    Phn[p*Cnext + o] = h;
    Pln[p*Cnext + o] = (_Float16)(r - (float)h);
  }
}

// ---------- MFMA conv5: 128 pts x 128 outs per block, LDS-staged, fused stats epilogue ----------
__global__ __launch_bounds__(256) void k_conv5m(const __hip_bfloat16* __restrict__ xcb,
    const __hip_bfloat16* __restrict__ w5b,
    float* __restrict__ pmax, float* __restrict__ pmin,
    float* __restrict__ psum, float* __restrict__ psq)
{
  __shared__ __align__(16) char smem[20480];
  __hip_bfloat16* As = (__hip_bfloat16*)smem;
  __hip_bfloat16* Bs = (__hip_bfloat16*)(smem + 10240);
  float* red = (float*)smem;
  int t = threadIdx.x, w = t >> 6, lane = t & 63, m = lane & 15, quad = lane >> 4;
  int nbk = blockIdx.x;
  int b = blockIdx.z;
  int o0 = blockIdx.y * 128;
  int n0 = nbk * 128;
  const __hip_bfloat16* Abase = xcb + (size_t)(b*NN + n0)*XCCH;
  const __hip_bfloat16* Bbase = w5b + (size_t)o0*XCCH;
  f32x4 acc[2][8];
  #pragma unroll
  for (int s=0;s<2;s++)
    #pragma unroll
    for (int j=0;j<8;j++){ f32x4 z = {0.f,0.f,0.f,0.f}; acc[s][j] = z; }
  int r = t >> 1;
  int sg0 = t & 1;
  for (int ch=0; ch<16; ++ch){
    int c0 = ch*32;
    #pragma unroll
    for (int k=0;k<2;k++){
      int seg = sg0 + 2*k;
      int go = c0 + seg*8;
      *(s8v*)&As[r*40 + seg*8] = *(const s8v*)&Abase[(size_t)r*XCCH + go];
      *(s8v*)&Bs[r*40 + seg*8] = *(const s8v*)&Bbase[(size_t)r*XCCH + go];
    }
    __syncthreads();
    s8v a0 = *(const s8v*)&As[(w*32 + m)*40 + quad*8];
    s8v a1 = *(const s8v*)&As[(w*32 + 16 + m)*40 + quad*8];
    #pragma unroll
    for (int j=0;j<8;j++){
      s8v bf = *(const s8v*)&Bs[(j*16 + m)*40 + quad*8];
      acc[0][j] = __builtin_amdgcn_mfma_f32_16x16x32_bf16(a0, bf, acc[0][j], 0, 0, 0);
      acc[1][j] = __builtin_amdgcn_mfma_f32_16x16x32_bf16(a1, bf, acc[1][j], 0, 0, 0);
    }
    __syncthreads();
  }
  float mx[8], mn[8], sm[8], sq[8];
  #pragma unroll
  for (int j=0;j<8;j++){
    mx[j] = -3.4e38f; mn[j] = 3.4e38f; sm[j] = 0.f; sq[j] = 0.f;
    #pragma unroll
    for (int s=0;s<2;s++){
      f32x4 a = acc[s][j];
      #pragma unroll
      for (int rg=0; rg<4; rg++){
        float v = a[rg];
        mx[j] = fmaxf(mx[j], v); mn[j] = fminf(mn[j], v);
        sm[j] += v; sq[j] += v*v;
      }
    }
  }
  #pragma unroll
  for (int j=0;j<8;j++){
    #pragma unroll
    for (int off=16; off<=32; off<<=1){
      mx[j] = fmaxf(mx[j], __shfl_xor(mx[j], off));
      mn[j] = fminf(mn[j], __shfl_xor(mn[j], off));
      sm[j] += __shfl_xor(sm[j], off);
      sq[j] += __shfl_xor(sq[j], off);
    }
  }
  if (quad == 0){
    #pragma unroll
    for (int j=0;j<8;j++){
      int c = j*16 + m;
      red[(0*4 + w)*128 + c] = mx[j];
      red[(1*4 + w)*128 + c] = mn[j];
      red[(2*4 + w)*128 + c] = sm[j];
      red[(3*4 + w)*128 + c] = sq[j];
    }
  }
  __syncthreads();
  if (t < 128){
    int c = t;
    float MX = red[(0*4+0)*128+c], MN = red[(1*4+0)*128+c];
    float S  = red[(2*4+0)*128+c], Q  = red[(3*4+0)*128+c];
    #pragma unroll
    for (int u=1;u<4;u++){
      MX = fmaxf(MX, red[(0*4+u)*128+c]);
      MN = fminf(MN, red[(1*4+u)*128+c]);
      S += red[(2*4+u)*128+c];
      Q += red[(3*4+u)*128+c];
    }
    size_t ii = ((size_t)b*1024 + o0 + c)*16 + nbk;
    pmax[ii] = MX; pmin[ii] = MN; psum[ii] = S; psq[ii] = Q;
  }
}

__global__ __launch_bounds__(256) void k_stats5(const float* __restrict__ psum, const float* __restrict__ psq,
    const float* __restrict__ g5, const float* __restrict__ b5,
    float* __restrict__ sc5, float* __restrict__ sh5){
  int o = blockIdx.x*256 + threadIdx.x;
  float s=0.f, s2=0.f;
  for (int b=0;b<BB;b++){
    const float* ps = &psum[((size_t)b*1024 + o)*16];
    const float* pq = &psq [((size_t)b*1024 + o)*16];
    #pragma unroll
    for (int u=0;u<16;u++){ s += ps[u]; s2 += pq[u]; }
  }
  float cnt = (float)(BB*NN);
  float mean = s/cnt;
  float var = s2/cnt - mean*mean;
  float sc = g5[o] / sqrtf(var + LEPS);
  sc5[o] = sc;
  sh5[o] = b5[o] - mean*sc;
}

__global__ __launch_bounds__(256) void k_apply5(const float* __restrict__ pmax, const float* __restrict__ pmin,
    const float* __restrict__ sc5, const float* __restrict__ sh5, float* __restrict__ out){
  int i = blockIdx.x*256 + threadIdx.x;
  int o = i & 1023;
  float sc = sc5[o];
  float v;
  if (sc >= 0.f){
    const float* p = &pmax[(size_t)i*16];
    v = p[0];
    #pragma unroll
    for (int u=1;u<16;u++) v = fmaxf(v, p[u]);
  } else {
    const float* p = &pmin[(size_t)i*16];
    v = p[0];
    #pragma unroll
    for (int u=1;u<16;u++) v = fminf(v, p[u]);
  }
  out[i] = lrelu(v*sc + sh5[o]);
}

extern "C" void kernel_launch(void* const* d_in, const int* in_sizes, int n_in,
                              void* d_out, int out_size, void* d_ws, size_t ws_size,
                              hipStream_t stream){
  const float* x  = (const float*)d_in[0];
  const float* w1 = (const float*)d_in[1];
  const float* g1 = (const float*)d_in[2];
  const float* b1 = (const float*)d_in[3];
  const float* w2 = (const float*)d_in[4];
  const float* g2 = (const float*)d_in[5];
  const float* b2 = (const float*)d_in[6];
  const float* w3 = (const float*)d_in[7];
  const float* g3 = (const float*)d_in[8];
  const float* b3 = (const float*)d_in[9];
  const float* w4 = (const float*)d_in[10];
  const float* g4 = (const float*)d_in[11];
  const float* b4 = (const float*)d_in[12];
  const float* w5 = (const float*)d_in[13];
  const float* g5 = (const float*)d_in[14];
  const float* b5 = (const float*)d_in[15];
  float* out = (float*)d_out;
  float* ws = (float*)d_ws;

  const size_t F_PD   = 0;
  const size_t F_XT0  = F_PD   + (size_t)BB*NN*NN;
  const size_t F_XC   = F_XT0  + (size_t)BB*NN*4;
  const size_t F_CHS  = F_XC   + (size_t)BB*NN*XCCH;
  const size_t F_CHQ  = F_CHS  + (size_t)NSLOT*256;
  const size_t F_SCL  = F_CHQ  + (size_t)NSLOT*256;
  const size_t F_SHF  = F_SCL  + 256;
  const size_t F_SQ   = F_SHF  + 256;
  const size_t F_IDX  = F_SQ   + (size_t)BB*NN;
  const size_t F_PMAX = F_IDX  + (size_t)BB*NN*KK;
  const size_t F_PMIN = F_PMAX + (size_t)BB*1024*8;
  const size_t F_PSUM = F_PMIN + (size_t)BB*1024*8;
  const size_t F_PSQ  = F_PSUM + (size_t)BB*1024*8;
  const size_t F_SC5  = F_PSQ  + (size_t)BB*1024*8;
  const size_t F_SH5  = F_SC5  + 1024;
  const size_t F_XCB  = F_SH5  + 1024;
  const size_t F_WB   = F_XCB  + (size_t)BB*NN*XCCH/2;      // wb region (bf16)
  const size_t F_PH   = F_WB   + 278528;                    // Ph: BB*NN*128 f16 = 1048576 floats
  const size_t F_PL   = F_PH   + 1048576;

  float* pd    = ws + F_PD;
  float* udb   = pd;                          // alias pd (pd dead after k_topk); <=8.4M floats
  float* w2buf = pd + (size_t)12*1024*1024;   // fp32 W2 (<=65536 floats), layers 1-3
  _Float16* W2h = (_Float16*)(pd + (size_t)12*1024*1024 + 65536);  // layer-4 split (65536 f16)
  _Float16* W2l = W2h + 65536;
  float* ymax  = pd + (size_t)16*1024*1024;
  float* ymin  = pd + (size_t)21*1024*1024;
  // conv5 partials live in the pd region (dead after last k_apply): 16 slots per (b,o)
  float* pmax  = pd;
  float* pmin  = pd + (size_t)(1<<20);
  float* psum  = pd + (size_t)(2<<20);
  float* psq   = pd + (size_t)(3<<20);
  float* xt0   = ws + F_XT0;
  float* xc    = ws + F_XC;
  float* chsum = ws + F_CHS;
  float* chsq  = ws + F_CHQ;
  float* scl   = ws + F_SCL;
  float* shf   = ws + F_SHF;
  float* sqb   = ws + F_SQ;
  int*   idxb  = (int*)(ws + F_IDX);
  float* sc5   = ws + F_SC5;
  float* sh5   = ws + F_SH5;
  __hip_bfloat16* xcb = (__hip_bfloat16*)(ws + F_XCB);
  __hip_bfloat16* wb  = (__hip_bfloat16*)(ws + F_WB);
  __hip_bfloat16* w5b = wb + 32768;    // 1024x512
  _Float16* Ph  = (_Float16*)(ws + F_PH);
  _Float16* Pl  = (_Float16*)(ws + F_PL);

  (void)in_sizes; (void)n_in; (void)out_size; (void)ws_size;

  k_transpose<<<64, 256, 0, stream>>>(x, xt0);
  k_cvtw<<<(524288+255)/256, 256, 0, stream>>>(w5, w5b, 512, 0, 512, 512, 524288);

  struct LayerP { const float* P; int stride; int Ci; int CiD; int Cpad;
                  const float* W; const float* g; const float* b; int Oi; int off; };
  LayerP L[4] = {
    { xt0,    4,   3,   4,   32,  w1, g1, b1,  64, 0   },
    { xc,     512, 64,  64,  64,  w2, g2, b2,  64, 64  },
    { xc+64,  512, 64,  64,  64,  w3, g3, b3, 128, 128 },
    { xc+128, 512, 128, 128, 128, w4, g4, b4, 256, 256 },
  };
  // next-layer split width written by k_apply (0 = none), and whether fp32 xc is needed
  int CnextA[4]  = { 64, 64, 128, 0 };
  int writeXcA[4] = { 1, 1, 0, 0 };

  for (int l=0; l<4; ++l){
    int Cpad = L[l].Cpad, nchunk = Cpad/32;
    int Oi = L[l].Oi, Ci = L[l].Ci;
    int ostr = 2*Oi;
    if (l == 0)
      k_split<<<(BB*NN*Cpad+255)/256, 256, 0, stream>>>(L[l].P, L[l].stride, L[l].CiD, Cpad, Ph, Pl);
    k_sqs<<<64, 256, 0, stream>>>(Ph, Pl, Cpad, sqb);
    k_distm<<<dim3(136,1,8), 256, 0, stream>>>(Ph, Pl, Cpad, nchunk, sqb, pd);
    k_topk<<<BB*NN/4, 256, 0, stream>>>(pd, idxb);
    hipMemsetAsync(chsum, 0, (size_t)NSLOT*256*2*sizeof(float), stream);
    if (l < 3){
      // exact fp32 U/D GEMM (feeds later knn graphs -> must stay fp32-exact)
      k_wprep<<<(2*Oi*Ci+255)/256, 256, 0, stream>>>(L[l].W, Ci, Oi, w2buf);
      k_gemmud<<<dim3(BB*NN/64, ostr/64), 256, 0, stream>>>(L[l].P, L[l].stride, Ci, w2buf, ostr, udb);
    } else {
      // layer 4: no downstream knn -> f16-split MFMA GEMM is numerically safe (continuous)
      k_wprep2<<<(2*Oi*Cpad+255)/256, 256, 0, stream>>>(L[l].W, Ci, Cpad, Oi, W2h, W2l);
      k_gemmudm<<<dim3(BB*NN/128, ostr/128), 256, 0, stream>>>(Ph, Pl, Cpad, nchunk, W2h, W2l, ostr, udb);
    }
    k_edge<<<dim3(BB*NN/16, Oi/64), 256, 0, stream>>>(udb, ostr, Oi, idxb, ymax, ymin, chsum, chsq);
    k_bnstats<<<1, 256, 0, stream>>>(chsum, chsq, L[l].g, L[l].b, scl, shf, Oi);
    k_apply<<<(BB*NN*Oi + 255)/256, 256, 0, stream>>>(ymax, ymin, scl, shf, xc, xcb, L[l].off, Oi,
                                                      Ph, Pl, CnextA[l], writeXcA[l]);
  }

  k_conv5m<<<dim3(16, 8, BB), 256, 0, stream>>>(xcb, w5b, pmax, pmin, psum, psq);
  k_stats5<<<4, 256, 0, stream>>>(psum, psq, g5, b5, sc5, sh5);
  k_apply5<<<(BB*1024)/256, 256, 0, stream>>>(pmax, pmin, sc5, sh5, out);
}

// Round 14
// 598.974 us; speedup vs baseline: 1.2192x; 1.0792x over previous
//
#include <hip/hip_runtime.h>
#include <hip/hip_bf16.h>
#include <math.h>

#define BB 8
#define NN 2048
#define KK 20
#define XCCH 512
#define NSLOT 64
#define LEPS 1e-5f
#define NEGINF -3.4e38f

typedef __attribute__((ext_vector_type(8))) short s8v;
typedef __attribute__((ext_vector_type(8))) _Float16 h8v;
typedef __attribute__((ext_vector_type(4))) float f32x4;

__device__ __forceinline__ float lrelu(float x){ return x >= 0.f ? x : 0.2f*x; }

// ---------- transpose x (B,3,N) -> xt0 (B*N,4) fp32 ----------
__global__ __launch_bounds__(256) void k_transpose(const float* __restrict__ x, float* __restrict__ xt){
  int i = blockIdx.x*256 + threadIdx.x;
  if (i >= BB*NN) return;
  int b = i >> 11, n = i & (NN-1);
  float4 v;
  v.x = x[(b*3+0)*NN + n];
  v.y = x[(b*3+1)*NN + n];
  v.z = x[(b*3+2)*NN + n];
  v.w = 0.f;
  reinterpret_cast<float4*>(xt)[i] = v;
}

// ---------- weight fp32 -> bf16 slice with K padding ----------
__global__ __launch_bounds__(256) void k_cvtw(const float* __restrict__ W, __hip_bfloat16* __restrict__ Wb,
                                              int Cs, int coff, int Ccnt, int Cpad, int total){
  int i = blockIdx.x*256 + threadIdx.x;
  if (i >= total) return;
  int o = i / Cpad, c = i - o*Cpad;
  Wb[i] = (c < Ccnt) ? __float2bfloat16(W[(size_t)o*Cs + coff + c]) : __float2bfloat16(0.f);
}

// ---------- split P fp32 -> hi/lo f16 (Cpad cols, zero-padded); used only for layer 1 (xt0) ----------
__global__ __launch_bounds__(256) void k_split(const float* __restrict__ P, int stride, int Ci, int Cpad,
    _Float16* __restrict__ Ph, _Float16* __restrict__ Pl){
  int i = blockIdx.x*256 + threadIdx.x;
  if (i >= BB*NN*Cpad) return;
  int p = i / Cpad, c = i - p*Cpad;
  float v = (c < Ci) ? P[(size_t)p*stride + c] : 0.f;
  _Float16 h = (_Float16)v;
  float r = v - (float)h;
  Ph[i] = h;
  Pl[i] = (_Float16)r;
}

// ---------- squared norms (vectorized, bit-identical order) + zero chsum/chsq ----------
__global__ __launch_bounds__(256) void k_sqs(const _Float16* __restrict__ Ph,
    const _Float16* __restrict__ Pl, int Cpad, float* __restrict__ sq,
    float* __restrict__ chz){
  int i = blockIdx.x*256 + threadIdx.x;
  if (i >= BB*NN) return;
  chz[i] = 0.f;                 // chsum/chsq are contiguous: 2*NSLOT*256 = 32768 floats
  chz[i + 16384] = 0.f;
  const h8v* ph = (const h8v*)(Ph + (size_t)i*Cpad);
  const h8v* pl = (const h8v*)(Pl + (size_t)i*Cpad);
  float s = 0.f;
  int n8 = Cpad >> 3;
  for (int c8 = 0; c8 < n8; ++c8){
    h8v vh = ph[c8], vl = pl[c8];
    #pragma unroll
    for (int e=0;e<8;e++){
      float v = (float)vh[e] + (float)vl[e];
      s += v*v;
    }
  }
  sq[i] = s;
}

// ---------- MFMA pairwise score, SYMMETRIC: only lower-triangle block pairs ----------
__global__ __launch_bounds__(256) void k_distm(
    const _Float16* __restrict__ Ph, const _Float16* __restrict__ Pl,
    int Cpad, int nchunk, const float* __restrict__ sq, float* __restrict__ pd)
{
  __shared__ _Float16 Ah[128*40];
  __shared__ _Float16 Al[128*40];
  __shared__ _Float16 Bh[128*40];
  __shared__ _Float16 Bl[128*40];
  int t = threadIdx.x;
  int w = t >> 6, lane = t & 63, m = lane & 15, quad = lane >> 4;
  int b = blockIdx.z;
  int i = blockIdx.x;
  int by = (int)((sqrtf(8.f*(float)i + 1.f) - 1.f) * 0.5f);
  while ((by+1)*(by+2)/2 <= i) by++;
  while (by*(by+1)/2 > i) by--;
  int bx = i - by*(by+1)/2;           // bx <= by
  int n0 = by * 128, m0 = bx * 128;
  const _Float16* PhB = Ph + (size_t)b*NN*Cpad;
  const _Float16* PlB = Pl + (size_t)b*NN*Cpad;
  f32x4 acc[2][8];
  #pragma unroll
  for (int s=0;s<2;s++)
    #pragma unroll
    for (int j=0;j<8;j++){ f32x4 z = {0.f,0.f,0.f,0.f}; acc[s][j] = z; }
  int r = t >> 1;
  int sg0 = t & 1;
  for (int ch=0; ch<nchunk; ++ch){
    int c0 = ch*32;
    #pragma unroll
    for (int k=0;k<2;k++){
      int seg = sg0 + 2*k;
      int go = c0 + seg*8;
      size_t an = (size_t)(n0+r)*Cpad + go;
      size_t bm = (size_t)(m0+r)*Cpad + go;
      *(h8v*)&Ah[r*40 + seg*8] = *(const h8v*)&PhB[an];
      *(h8v*)&Al[r*40 + seg*8] = *(const h8v*)&PlB[an];
      *(h8v*)&Bh[r*40 + seg*8] = *(const h8v*)&PhB[bm];
      *(h8v*)&Bl[r*40 + seg*8] = *(const h8v*)&PlB[bm];
    }
    __syncthreads();
    h8v ah0 = *(const h8v*)&Ah[(w*32 + m)*40 + quad*8];
    h8v al0 = *(const h8v*)&Al[(w*32 + m)*40 + quad*8];
    h8v ah1 = *(const h8v*)&Ah[(w*32 + 16 + m)*40 + quad*8];
    h8v al1 = *(const h8v*)&Al[(w*32 + 16 + m)*40 + quad*8];
    #pragma unroll
    for (int j=0;j<8;j++){
      h8v bh = *(const h8v*)&Bh[(j*16 + m)*40 + quad*8];
      h8v bl = *(const h8v*)&Bl[(j*16 + m)*40 + quad*8];
      acc[0][j] = __builtin_amdgcn_mfma_f32_16x16x32_f16(ah0, bh, acc[0][j], 0, 0, 0);
      acc[0][j] = __builtin_amdgcn_mfma_f32_16x16x32_f16(ah0, bl, acc[0][j], 0, 0, 0);
      acc[0][j] = __builtin_amdgcn_mfma_f32_16x16x32_f16(al0, bh, acc[0][j], 0, 0, 0);
      acc[0][j] = __builtin_amdgcn_mfma_f32_16x16x32_f16(al0, bl, acc[0][j], 0, 0, 0);
      acc[1][j] = __builtin_amdgcn_mfma_f32_16x16x32_f16(ah1, bh, acc[1][j], 0, 0, 0);
      acc[1][j] = __builtin_amdgcn_mfma_f32_16x16x32_f16(ah1, bl, acc[1][j], 0, 0, 0);
      acc[1][j] = __builtin_amdgcn_mfma_f32_16x16x32_f16(al1, bh, acc[1][j], 0, 0, 0);
      acc[1][j] = __builtin_amdgcn_mfma_f32_16x16x32_f16(al1, bl, acc[1][j], 0, 0, 0);
    }
    __syncthreads();
  }
  float sqm_[8];
  #pragma unroll
  for (int j=0;j<8;j++) sqm_[j] = sq[b*NN + m0 + j*16 + m];
  float sqn_[2][4];
  #pragma unroll
  for (int s=0;s<2;s++)
    #pragma unroll
    for (int rg=0; rg<4; rg++)
      sqn_[s][rg] = sq[b*NN + n0 + w*32 + s*16 + quad*4 + rg];
  #pragma unroll
  for (int s=0;s<2;s++){
    #pragma unroll
    for (int rg=0; rg<4; rg++){
      size_t rowoff = ((size_t)b*NN + n0 + w*32 + s*16 + quad*4 + rg)*NN + m0 + m;
      #pragma unroll
      for (int j=0;j<8;j++){
        pd[rowoff + j*16] = 2.f*acc[s][j][rg] - sqn_[s][rg] - sqm_[j];
      }
    }
  }
  if (bx != by){
    #pragma unroll
    for (int s=0;s<2;s++){
      #pragma unroll
      for (int j=0;j<8;j++){
        size_t moff = ((size_t)b*NN + m0 + j*16 + m)*NN + n0 + w*32 + s*16 + quad*4;
        float4 v;
        v.x = 2.f*acc[s][j][0] - sqm_[j] - sqn_[s][0];
        v.y = 2.f*acc[s][j][1] - sqm_[j] - sqn_[s][1];
        v.z = 2.f*acc[s][j][2] - sqm_[j] - sqn_[s][2];
        v.w = 2.f*acc[s][j][3] - sqm_[j] - sqn_[s][3];
        *(float4*)&pd[moff] = v;
      }
    }
  }
}

// ---------- top-20 per row: bulk extraction, lazy top-3 state (rescan only after 2 pops) ----------
#define TK_REP32(F) F(0)F(1)F(2)F(3)F(4)F(5)F(6)F(7)F(8)F(9)F(10)F(11)F(12)F(13)F(14)F(15) \
                    F(16)F(17)F(18)F(19)F(20)F(21)F(22)F(23)F(24)F(25)F(26)F(27)F(28)F(29)F(30)F(31)
#define TK3_SCAN(u) { bool c1 = r##u > p1; bool c2 = r##u > p2; bool c3 = r##u > p3; \
    p3 = c2 ? p2 : (c3 ? r##u : p3); \
    i2 = c1 ? i1 : (c2 ? u : i2); \
    p2 = c1 ? p1 : (c2 ? r##u : p2); \
    i1 = c1 ? u : i1; \
    p1 = c1 ? r##u : p1; }
#define TK3_RSCAN(u) { float vv = ((rem >> u) & 1u) ? NEGINF : r##u; \
    bool c1 = vv > p1; bool c2 = vv > p2; bool c3 = vv > p3; \
    p3 = c2 ? p2 : (c3 ? vv : p3); \
    i2 = c1 ? i1 : (c2 ? u : i2); \
    p2 = c1 ? p1 : (c2 ? vv : p2); \
    i1 = c1 ? u : i1; \
    p1 = c1 ? vv : p1; }

__global__ __launch_bounds__(256) void k_topk(const float* __restrict__ pd, int* __restrict__ idxo){
  int t = threadIdx.x;
  int l = t & 63;
  int row = blockIdx.x*4 + (t >> 6);
  const float4* rp = (const float4*)(pd + (size_t)row*NN);
  float4 q0 = rp[0*64+l], q1 = rp[1*64+l], q2 = rp[2*64+l], q3 = rp[3*64+l];
  float4 q4 = rp[4*64+l], q5 = rp[5*64+l], q6 = rp[6*64+l], q7 = rp[7*64+l];
  float r0 =q0.x, r1 =q0.y, r2 =q0.z, r3 =q0.w, r4 =q1.x, r5 =q1.y, r6 =q1.z, r7 =q1.w;
  float r8 =q2.x, r9 =q2.y, r10=q2.z, r11=q2.w, r12=q3.x, r13=q3.y, r14=q3.z, r15=q3.w;
  float r16=q4.x, r17=q4.y, r18=q4.z, r19=q4.w, r20=q5.x, r21=q5.y, r22=q5.z, r23=q5.w;
  float r24=q6.x, r25=q6.y, r26=q6.z, r27=q6.w, r28=q7.x, r29=q7.y, r30=q7.z, r31=q7.w;
  float p1 = NEGINF, p2 = NEGINF, p3 = NEGINF;
  int i1 = 0, i2 = 0, nv = 3;
  unsigned rem = 0u;
  TK_REP32(TK3_SCAN)
  int* orow = idxo + (size_t)row*KK;
  int got = 0;
  while (got < KK){
    float M2 = p2;
    #pragma unroll
    for (int off=1; off<64; off<<=1) M2 = fmaxf(M2, __shfl_xor(M2, off));
    bool ex = (p1 >= M2);
    unsigned long long ball = __ballot(ex);
    int cnt = __popcll(ball);
    int take = KK - got;
    if (cnt <= take){
      if (ex){
        int pos = got + __popcll(ball & ((1ull << l) - 1ull));
        orow[pos] = ((i1 >> 2) << 8) | (l << 2) | (i1 & 3);
        rem |= 1u << i1;
        p1 = p2; i1 = i2; p2 = p3; nv--;
      }
      got += cnt;
      if (got < KK && nv < 2){
        p1 = NEGINF; p2 = NEGINF; p3 = NEGINF; i1 = 0; i2 = 0;
        TK_REP32(TK3_RSCAN)
        nv = 3;
      }
    } else {
      for (int tt = 0; tt < take; ++tt){
        float wv = p1;
        #pragma unroll
        for (int off=1; off<64; off<<=1) wv = fmaxf(wv, __shfl_xor(wv, off));
        int gi = (p1 == wv) ? (((i1 >> 2) << 8) | (l << 2) | (i1 & 3)) : 0x7FFFFFFF;
        int cand = gi;
        #pragma unroll
        for (int off=1; off<64; off<<=1){
          int oc = __shfl_xor(cand, off);
          cand = oc < cand ? oc : cand;
        }
        if (gi == cand){
          orow[got + tt] = cand;
          p1 = NEGINF;
        }
      }
      got = KK;
    }
  }
}

// ---------- U/D GEMM fp32 (exact, layers 1-3): W2 rows built inline in staging ----------
__global__ __launch_bounds__(256) void k_gemmud(const float* __restrict__ P, int stride, int Ci,
    const float* __restrict__ W, int Oi, int ostr, float* __restrict__ udb){
  __shared__ float Pt[16*68];
  __shared__ float Wt[16*68];
  int t = threadIdx.x, ty = t >> 4, tx = t & 15;
  int p0 = blockIdx.x*64, o0 = blockIdx.y*64;
  int twoCi = 2*Ci;
  float acc[4][4];
  #pragma unroll
  for (int i=0;i<4;i++)
    #pragma unroll
    for (int j=0;j<4;j++) acc[i][j]=0.f;
  for (int c0 = 0; c0 < Ci; c0 += 16){
    #pragma unroll
    for (int q=0;q<4;q++){
      int e = t + 256*q;
      int r = e >> 4, cc = e & 15;
      int c = c0 + cc;
      bool ok = (c < Ci);
      Pt[cc*68 + r] = ok ? P[(size_t)(p0+r)*stride + c] : 0.f;
      float wv = 0.f;
      if (ok){
        int orow = o0 + r;
        if (orow < Oi) wv = W[(size_t)orow*twoCi + Ci + c];
        else { int o = orow - Oi; wv = W[(size_t)o*twoCi + c] - W[(size_t)o*twoCi + Ci + c]; }
      }
      Wt[cc*68 + r] = wv;
    }
    __syncthreads();
    #pragma unroll
    for (int j=0;j<16;j++){
      float4 av  = *(const float4*)&Pt[j*68 + ty*4];
      float4 bv4 = *(const float4*)&Wt[j*68 + tx*4];
      float a[4]  = {av.x, av.y, av.z, av.w};
      float bv[4] = {bv4.x, bv4.y, bv4.z, bv4.w};
      #pragma unroll
      for (int i=0;i<4;i++)
        #pragma unroll
        for (int jj=0;jj<4;jj++) acc[i][jj] += a[i]*bv[jj];
    }
    __syncthreads();
  }
  #pragma unroll
  for (int i=0;i<4;i++){
    *(float4*)&udb[(size_t)(p0+ty*4+i)*ostr + o0 + tx*4] =
      make_float4(acc[i][0], acc[i][1], acc[i][2], acc[i][3]);
  }
}

// ---------- U/D GEMM via MFMA f16-split (LAYER 4 ONLY); W2 split computed inline ----------
__global__ __launch_bounds__(256) void k_gemmudm(
    const _Float16* __restrict__ Ph, const _Float16* __restrict__ Pl,
    int Cpad, int nchunk,
    const float* __restrict__ W, int Ci, int Oi,
    int ostr, float* __restrict__ udb)
{
  __shared__ _Float16 Ah[128*40];
  __shared__ _Float16 Al[128*40];
  __shared__ _Float16 Bh[128*40];
  __shared__ _Float16 Bl[128*40];
  int t = threadIdx.x;
  int w = t >> 6, lane = t & 63, m = lane & 15, quad = lane >> 4;
  int p0 = blockIdx.x * 128, o0 = blockIdx.y * 128;
  int twoCi = 2*Ci;
  f32x4 acc[2][8];
  #pragma unroll
  for (int s=0;s<2;s++)
    #pragma unroll
    for (int j=0;j<8;j++){ f32x4 z = {0.f,0.f,0.f,0.f}; acc[s][j] = z; }
  int r = t >> 1;
  int sg0 = t & 1;
  int orow = o0 + r;
  for (int ch=0; ch<nchunk; ++ch){
    int c0 = ch*32;
    #pragma unroll
    for (int k=0;k<2;k++){
      int seg = sg0 + 2*k;
      int go = c0 + seg*8;
      size_t an = (size_t)(p0+r)*Cpad + go;
      *(h8v*)&Ah[r*40 + seg*8] = *(const h8v*)&Ph[an];
      *(h8v*)&Al[r*40 + seg*8] = *(const h8v*)&Pl[an];
      h8v hh, ll;
      #pragma unroll
      for (int e=0;e<8;e++){
        int c = go + e;
        float v = 0.f;
        if (c < Ci){
          if (orow < Oi) v = W[(size_t)orow*twoCi + Ci + c];
          else { int o = orow - Oi; v = W[(size_t)o*twoCi + c] - W[(size_t)o*twoCi + Ci + c]; }
        }
        _Float16 h = (_Float16)v;
        hh[e] = h;
        ll[e] = (_Float16)(v - (float)h);
      }
      *(h8v*)&Bh[r*40 + seg*8] = hh;
      *(h8v*)&Bl[r*40 + seg*8] = ll;
    }
    __syncthreads();
    h8v ah0 = *(const h8v*)&Ah[(w*32 + m)*40 + quad*8];
    h8v al0 = *(const h8v*)&Al[(w*32 + m)*40 + quad*8];
    h8v ah1 = *(const h8v*)&Ah[(w*32 + 16 + m)*40 + quad*8];
    h8v al1 = *(const h8v*)&Al[(w*32 + 16 + m)*40 + quad*8];
    #pragma unroll
    for (int j=0;j<8;j++){
      h8v bh = *(const h8v*)&Bh[(j*16 + m)*40 + quad*8];
      h8v bl = *(const h8v*)&Bl[(j*16 + m)*40 + quad*8];
      acc[0][j] = __builtin_amdgcn_mfma_f32_16x16x32_f16(ah0, bh, acc[0][j], 0, 0, 0);
      acc[0][j] = __builtin_amdgcn_mfma_f32_16x16x32_f16(ah0, bl, acc[0][j], 0, 0, 0);
      acc[0][j] = __builtin_amdgcn_mfma_f32_16x16x32_f16(al0, bh, acc[0][j], 0, 0, 0);
      acc[0][j] = __builtin_amdgcn_mfma_f32_16x16x32_f16(al0, bl, acc[0][j], 0, 0, 0);
      acc[1][j] = __builtin_amdgcn_mfma_f32_16x16x32_f16(ah1, bh, acc[1][j], 0, 0, 0);
      acc[1][j] = __builtin_amdgcn_mfma_f32_16x16x32_f16(ah1, bl, acc[1][j], 0, 0, 0);
      acc[1][j] = __builtin_amdgcn_mfma_f32_16x16x32_f16(al1, bh, acc[1][j], 0, 0, 0);
      acc[1][j] = __builtin_amdgcn_mfma_f32_16x16x32_f16(al1, bl, acc[1][j], 0, 0, 0);
    }
    __syncthreads();
  }
  #pragma unroll
  for (int s=0;s<2;s++){
    int rbase = w*32 + s*16 + quad*4;
    #pragma unroll
    for (int rg=0; rg<4; rg++){
      size_t rowoff = (size_t)(p0 + rbase + rg)*ostr + o0 + m;
      #pragma unroll
      for (int j=0;j<8;j++){
        udb[rowoff + j*16] = acc[s][j][rg];
      }
    }
  }
}

// ---------- edge gather-reduce: y[n,k,o] = U[nbr(n,k),o] + D[n,o] ----------
__global__ __launch_bounds__(256) void k_edge(const float* __restrict__ udb, int ostr, int Oi,
    const int* __restrict__ idxg,
    float* __restrict__ ymax, float* __restrict__ ymin,
    float* __restrict__ chsum, float* __restrict__ chsq){
  __shared__ int lidx[16*KK];
  __shared__ float reds[2][4][64];
  int t = threadIdx.x, w = t >> 6, lane = t & 63;
  int n0 = blockIdx.x*16;
  int b  = n0 >> 11;
  int o0 = blockIdx.y*64;
  for (int q=t; q<16*KK; q+=256) lidx[q] = idxg[(size_t)n0*KK + q];
  __syncthreads();
  int o = o0 + lane;
  float ws_s = 0.f, ws_q = 0.f;
  #pragma unroll
  for (int p=0;p<4;p++){
    int pl = w*4 + p;
    int n = n0 + pl;
    float mx = -3.4e38f, mn = 3.4e38f, s = 0.f, s2 = 0.f;
    #pragma unroll
    for (int k=0;k<KK;k++){
      int nb = lidx[pl*KK + k];
      float u = udb[(size_t)((b<<11) + nb)*ostr + o];
      mx = fmaxf(mx, u); mn = fminf(mn, u);
      s += u; s2 += u*u;
    }
    float Dv = udb[(size_t)n*ostr + Oi + o];
    size_t base = (size_t)n*256 + o;
    ymax[base] = mx + Dv;
    ymin[base] = mn + Dv;
    ws_s += s + (float)KK*Dv;
    ws_q += s2 + 2.f*Dv*s + (float)KK*Dv*Dv;
  }
  reds[0][w][lane] = ws_s;
  reds[1][w][lane] = ws_q;
  __syncthreads();
  if (w == 0){
    float s = reds[0][0][lane] + reds[0][1][lane] + reds[0][2][lane] + reds[0][3][lane];
    float q = reds[1][0][lane] + reds[1][1][lane] + reds[1][2][lane] + reds[1][3][lane];
    int slot = blockIdx.x & (NSLOT-1);
    atomicAdd(&chsum[slot*256 + o], s);
    atomicAdd(&chsq [slot*256 + o], q);
  }
}

// ---------- BN stats finalize ----------
__global__ __launch_bounds__(256) void k_bnstats(const float* __restrict__ chsum, const float* __restrict__ chsq,
    const float* __restrict__ g, const float* __restrict__ bet,
    float* __restrict__ scl, float* __restrict__ shf, int Oi){
  int o = threadIdx.x;
  if (o >= Oi) return;
  float s=0.f, s2=0.f;
  for (int u=0;u<NSLOT;u++){ s += chsum[u*256+o]; s2 += chsq[u*256+o]; }
  float cnt = (float)(BB*NN*KK);
  float mean = s/cnt;
  float var = s2/cnt - mean*mean;
  float sc = g[o] / sqrtf(var + LEPS);
  scl[o] = sc;
  shf[o] = bet[o] - mean*sc;
}

// ---------- apply BN+LReLU; write xc (opt), bf16 xcb, and next-layer split Ph/Pl (opt) ----------
__global__ __launch_bounds__(256) void k_apply(const float* __restrict__ ymax, const float* __restrict__ ymin,
    const float* __restrict__ scl, const float* __restrict__ shf,
    float* __restrict__ xc, __hip_bfloat16* __restrict__ xcb, int off, int Oi,
    _Float16* __restrict__ Phn, _Float16* __restrict__ Pln, int Cnext, int writeXc){
  int i = blockIdx.x*256 + threadIdx.x;
  if (i >= BB*NN*Oi) return;
  int o = i & (Oi-1);
  size_t p = (size_t)((unsigned)i / (unsigned)Oi);
  float sc = scl[o];
  float v = (sc >= 0.f) ? ymax[p*256+o] : ymin[p*256+o];
  float r = lrelu(v*sc + shf[o]);
  if (writeXc) xc[p*XCCH + off + o] = r;
  xcb[p*XCCH + off + o] = __float2bfloat16(r);
  if (Cnext){
    _Float16 h = (_Float16)r;
    Phn[p*Cnext + o] = h;
    Pln[p*Cnext + o] = (_Float16)(r - (float)h);
  }
}

// ---------- MFMA conv5: 128 pts x 128 outs per block, LDS-staged, fused stats epilogue ----------
__global__ __launch_bounds__(256) void k_conv5m(const __hip_bfloat16* __restrict__ xcb,
    const __hip_bfloat16* __restrict__ w5b,
    float* __restrict__ pmax, float* __restrict__ pmin,
    float* __restrict__ psum, float* __restrict__ psq)
{
  __shared__ __align__(16) char smem[20480];
  __hip_bfloat16* As = (__hip_bfloat16*)smem;
  __hip_bfloat16* Bs = (__hip_bfloat16*)(smem + 10240);
  float* red = (float*)smem;
  int t = threadIdx.x, w = t >> 6, lane = t & 63, m = lane & 15, quad = lane >> 4;
  int nbk = blockIdx.x;
  int b = blockIdx.z;
  int o0 = blockIdx.y * 128;
  int n0 = nbk * 128;
  const __hip_bfloat16* Abase = xcb + (size_t)(b*NN + n0)*XCCH;
  const __hip_bfloat16* Bbase = w5b + (size_t)o0*XCCH;
  f32x4 acc[2][8];
  #pragma unroll
  for (int s=0;s<2;s++)
    #pragma unroll
    for (int j=0;j<8;j++){ f32x4 z = {0.f,0.f,0.f,0.f}; acc[s][j] = z; }
  int r = t >> 1;
  int sg0 = t & 1;
  for (int ch=0; ch<16; ++ch){
    int c0 = ch*32;
    #pragma unroll
    for (int k=0;k<2;k++){
      int seg = sg0 + 2*k;
      int go = c0 + seg*8;
      *(s8v*)&As[r*40 + seg*8] = *(const s8v*)&Abase[(size_t)r*XCCH + go];
      *(s8v*)&Bs[r*40 + seg*8] = *(const s8v*)&Bbase[(size_t)r*XCCH + go];
    }
    __syncthreads();
    s8v a0 = *(const s8v*)&As[(w*32 + m)*40 + quad*8];
    s8v a1 = *(const s8v*)&As[(w*32 + 16 + m)*40 + quad*8];
    #pragma unroll
    for (int j=0;j<8;j++){
      s8v bf = *(const s8v*)&Bs[(j*16 + m)*40 + quad*8];
      acc[0][j] = __builtin_amdgcn_mfma_f32_16x16x32_bf16(a0, bf, acc[0][j], 0, 0, 0);
      acc[1][j] = __builtin_amdgcn_mfma_f32_16x16x32_bf16(a1, bf, acc[1][j], 0, 0, 0);
    }
    __syncthreads();
  }
  float mx[8], mn[8], sm[8], sq[8];
  #pragma unroll
  for (int j=0;j<8;j++){
    mx[j] = -3.4e38f; mn[j] = 3.4e38f; sm[j] = 0.f; sq[j] = 0.f;
    #pragma unroll
    for (int s=0;s<2;s++){
      f32x4 a = acc[s][j];
      #pragma unroll
      for (int rg=0; rg<4; rg++){
        float v = a[rg];
        mx[j] = fmaxf(mx[j], v); mn[j] = fminf(mn[j], v);
        sm[j] += v; sq[j] += v*v;
      }
    }
  }
  #pragma unroll
  for (int j=0;j<8;j++){
    #pragma unroll
    for (int off=16; off<=32; off<<=1){
      mx[j] = fmaxf(mx[j], __shfl_xor(mx[j], off));
      mn[j] = fminf(mn[j], __shfl_xor(mn[j], off));
      sm[j] += __shfl_xor(sm[j], off);
      sq[j] += __shfl_xor(sq[j], off);
    }
  }
  if (quad == 0){
    #pragma unroll
    for (int j=0;j<8;j++){
      int c = j*16 + m;
      red[(0*4 + w)*128 + c] = mx[j];
      red[(1*4 + w)*128 + c] = mn[j];
      red[(2*4 + w)*128 + c] = sm[j];
      red[(3*4 + w)*128 + c] = sq[j];
    }
  }
  __syncthreads();
  if (t < 128){
    int c = t;
    float MX = red[(0*4+0)*128+c], MN = red[(1*4+0)*128+c];
    float S  = red[(2*4+0)*128+c], Q  = red[(3*4+0)*128+c];
    #pragma unroll
    for (int u=1;u<4;u++){
      MX = fmaxf(MX, red[(0*4+u)*128+c]);
      MN = fminf(MN, red[(1*4+u)*128+c]);
      S += red[(2*4+u)*128+c];
      Q += red[(3*4+u)*128+c];
    }
    size_t ii = ((size_t)b*1024 + o0 + c)*16 + nbk;
    pmax[ii] = MX; pmin[ii] = MN; psum[ii] = S; psq[ii] = Q;
  }
}

__global__ __launch_bounds__(256) void k_stats5(const float* __restrict__ psum, const float* __restrict__ psq,
    const float* __restrict__ g5, const float* __restrict__ b5,
    float* __restrict__ sc5, float* __restrict__ sh5){
  int o = blockIdx.x*256 + threadIdx.x;
  float s=0.f, s2=0.f;
  for (int b=0;b<BB;b++){
    const float* ps = &psum[((size_t)b*1024 + o)*16];
    const float* pq = &psq [((size_t)b*1024 + o)*16];
    #pragma unroll
    for (int u=0;u<16;u++){ s += ps[u]; s2 += pq[u]; }
  }
  float cnt = (float)(BB*NN);
  float mean = s/cnt;
  float var = s2/cnt - mean*mean;
  float sc = g5[o] / sqrtf(var + LEPS);
  sc5[o] = sc;
  sh5[o] = b5[o] - mean*sc;
}

__global__ __launch_bounds__(256) void k_apply5(const float* __restrict__ pmax, const float* __restrict__ pmin,
    const float* __restrict__ sc5, const float* __restrict__ sh5, float* __restrict__ out){
  int i = blockIdx.x*256 + threadIdx.x;
  int o = i & 1023;
  float sc = sc5[o];
  float v;
  if (sc >= 0.f){
    const float* p = &pmax[(size_t)i*16];
    v = p[0];
    #pragma unroll
    for (int u=1;u<16;u++) v = fmaxf(v, p[u]);
  } else {
    const float* p = &pmin[(size_t)i*16];
    v = p[0];
    #pragma unroll
    for (int u=1;u<16;u++) v = fminf(v, p[u]);
  }
  out[i] = lrelu(v*sc + sh5[o]);
}

extern "C" void kernel_launch(void* const* d_in, const int* in_sizes, int n_in,
                              void* d_out, int out_size, void* d_ws, size_t ws_size,
                              hipStream_t stream){
  const float* x  = (const float*)d_in[0];
  const float* w1 = (const float*)d_in[1];
  const float* g1 = (const float*)d_in[2];
  const float* b1 = (const float*)d_in[3];
  const float* w2 = (const float*)d_in[4];
  const float* g2 = (const float*)d_in[5];
  const float* b2 = (const float*)d_in[6];
  const float* w3 = (const float*)d_in[7];
  const float* g3 = (const float*)d_in[8];
  const float* b3 = (const float*)d_in[9];
  const float* w4 = (const float*)d_in[10];
  const float* g4 = (const float*)d_in[11];
  const float* b4 = (const float*)d_in[12];
  const float* w5 = (const float*)d_in[13];
  const float* g5 = (const float*)d_in[14];
  const float* b5 = (const float*)d_in[15];
  float* out = (float*)d_out;
  float* ws = (float*)d_ws;

  const size_t F_PD   = 0;
  const size_t F_XT0  = F_PD   + (size_t)BB*NN*NN;
  const size_t F_XC   = F_XT0  + (size_t)BB*NN*4;
  const size_t F_CHS  = F_XC   + (size_t)BB*NN*XCCH;
  const size_t F_CHQ  = F_CHS  + (size_t)NSLOT*256;
  const size_t F_SCL  = F_CHQ  + (size_t)NSLOT*256;
  const size_t F_SHF  = F_SCL  + 256;
  const size_t F_SQ   = F_SHF  + 256;
  const size_t F_IDX  = F_SQ   + (size_t)BB*NN;
  const size_t F_PMAX = F_IDX  + (size_t)BB*NN*KK;
  const size_t F_PMIN = F_PMAX + (size_t)BB*1024*8;
  const size_t F_PSUM = F_PMIN + (size_t)BB*1024*8;
  const size_t F_PSQ  = F_PSUM + (size_t)BB*1024*8;
  const size_t F_SC5  = F_PSQ  + (size_t)BB*1024*8;
  const size_t F_SH5  = F_SC5  + 1024;
  const size_t F_XCB  = F_SH5  + 1024;
  const size_t F_WB   = F_XCB  + (size_t)BB*NN*XCCH/2;      // wb region (bf16)
  const size_t F_PH   = F_WB   + 278528;                    // Ph: BB*NN*128 f16 = 1048576 floats
  const size_t F_PL   = F_PH   + 1048576;

  float* pd    = ws + F_PD;
  float* udb   = pd;                          // alias pd (pd dead after k_topk); <=8.4M floats
  float* ymax  = pd + (size_t)16*1024*1024;
  float* ymin  = pd + (size_t)21*1024*1024;
  // conv5 partials live in the pd region (dead after last k_apply): 16 slots per (b,o)
  float* pmax  = pd;
  float* pmin  = pd + (size_t)(1<<20);
  float* psum  = pd + (size_t)(2<<20);
  float* psq   = pd + (size_t)(3<<20);
  float* xt0   = ws + F_XT0;
  float* xc    = ws + F_XC;
  float* chsum = ws + F_CHS;
  float* chsq  = ws + F_CHQ;
  float* scl   = ws + F_SCL;
  float* shf   = ws + F_SHF;
  float* sqb   = ws + F_SQ;
  int*   idxb  = (int*)(ws + F_IDX);
  float* sc5   = ws + F_SC5;
  float* sh5   = ws + F_SH5;
  __hip_bfloat16* xcb = (__hip_bfloat16*)(ws + F_XCB);
  __hip_bfloat16* wb  = (__hip_bfloat16*)(ws + F_WB);
  __hip_bfloat16* w5b = wb + 32768;    // 1024x512
  _Float16* Ph  = (_Float16*)(ws + F_PH);
  _Float16* Pl  = (_Float16*)(ws + F_PL);

  (void)in_sizes; (void)n_in; (void)out_size; (void)ws_size;

  k_transpose<<<64, 256, 0, stream>>>(x, xt0);
  k_cvtw<<<(524288+255)/256, 256, 0, stream>>>(w5, w5b, 512, 0, 512, 512, 524288);

  struct LayerP { const float* P; int stride; int Ci; int CiD; int Cpad;
                  const float* W; const float* g; const float* b; int Oi; int off; };
  LayerP L[4] = {
    { xt0,    4,   3,   4,   32,  w1, g1, b1,  64, 0   },
    { xc,     512, 64,  64,  64,  w2, g2, b2,  64, 64  },
    { xc+64,  512, 64,  64,  64,  w3, g3, b3, 128, 128 },
    { xc+128, 512, 128, 128, 128, w4, g4, b4, 256, 256 },
  };
  // next-layer split width written by k_apply (0 = none), and whether fp32 xc is needed
  int CnextA[4]  = { 64, 64, 128, 0 };
  int writeXcA[4] = { 1, 1, 0, 0 };

  for (int l=0; l<4; ++l){
    int Cpad = L[l].Cpad, nchunk = Cpad/32;
    int Oi = L[l].Oi, Ci = L[l].Ci;
    int ostr = 2*Oi;
    if (l == 0)
      k_split<<<(BB*NN*Cpad+255)/256, 256, 0, stream>>>(L[l].P, L[l].stride, L[l].CiD, Cpad, Ph, Pl);
    k_sqs<<<64, 256, 0, stream>>>(Ph, Pl, Cpad, sqb, chsum);   // also zeroes chsum+chsq
    k_distm<<<dim3(136,1,8), 256, 0, stream>>>(Ph, Pl, Cpad, nchunk, sqb, pd);
    k_topk<<<BB*NN/4, 256, 0, stream>>>(pd, idxb);
    if (l < 3){
      // exact fp32 U/D GEMM (feeds later knn graphs -> must stay fp32-exact)
      k_gemmud<<<dim3(BB*NN/64, ostr/64), 256, 0, stream>>>(L[l].P, L[l].stride, Ci, L[l].W, Oi, ostr, udb);
    } else {
      // layer 4: no downstream knn -> f16-split MFMA GEMM is numerically safe (continuous)
      k_gemmudm<<<dim3(BB*NN/128, ostr/128), 256, 0, stream>>>(Ph, Pl, Cpad, nchunk, L[l].W, Ci, Oi, ostr, udb);
    }
    k_edge<<<dim3(BB*NN/16, Oi/64), 256, 0, stream>>>(udb, ostr, Oi, idxb, ymax, ymin, chsum, chsq);
    k_bnstats<<<1, 256, 0, stream>>>(chsum, chsq, L[l].g, L[l].b, scl, shf, Oi);
    k_apply<<<(BB*NN*Oi + 255)/256, 256, 0, stream>>>(ymax, ymin, scl, shf, xc, xcb, L[l].off, Oi,
                                                      Ph, Pl, CnextA[l], writeXcA[l]);
  }

  k_conv5m<<<dim3(16, 8, BB), 256, 0, stream>>>(xcb, w5b, pmax, pmin, psum, psq);
  k_stats5<<<4, 256, 0, stream>>>(psum, psq, g5, b5, sc5, sh5);
  k_apply5<<<(BB*1024)/256, 256, 0, stream>>>(pmax, pmin, sc5, sh5, out);
}